// Round 6
// baseline (1202.649 us; speedup 1.0000x reference)
//
#include <hip/hip_runtime.h>

#define S_TOT 7601
#define BATCH 2
#define BM (BATCH * S_TOT)   // 15202
#define DMODEL 256

typedef unsigned short bf16;
typedef __attribute__((ext_vector_type(8))) short v8s;
typedef __attribute__((ext_vector_type(4))) float v4f;

__device__ __forceinline__ float b2f(bf16 u) {
    union { unsigned int i; float f; } v;
    v.i = ((unsigned int)u) << 16;
    return v.f;
}
__device__ __forceinline__ bf16 f2b(float f) {
    union { unsigned int i; float f; } v;
    v.f = f;
    unsigned int r = v.i + 0x7FFFu + ((v.i >> 16) & 1u);
    return (bf16)(r >> 16);
}
__device__ __forceinline__ float ldin(const void* p, size_t i, int isf32) {
    return isf32 ? ((const float*)p)[i] : b2f(((const bf16*)p)[i]);
}

// async global->LDS, 16B per lane. LDS dest must be linear: wave-uniform base + lane*16.
#define GLDS16(gp, lp)                                                          \
    __builtin_amdgcn_global_load_lds(                                           \
        (const __attribute__((address_space(1))) unsigned int*)(gp),            \
        (__attribute__((address_space(3))) unsigned int*)(lp), 16, 0, 0)

// bijective XCD-chunked block remap (m204): consecutive logical blocks land on one XCD.
__device__ __forceinline__ void xcd_remap(int& bx, int& by) {
    int gx = gridDim.x, gy = gridDim.y;
    int nwg = gx * gy;
    int lin = blockIdx.y * gx + blockIdx.x;
    int q = nwg >> 3, r = nwg & 7;
    int xcd = lin & 7, idx = lin >> 3;
    int lin2 = (xcd < r ? xcd * (q + 1) : r * (q + 1) + (xcd - r) * q) + idx;
    bx = lin2 % gx;
    by = lin2 / gx;
}

// ---------------- dtype probe ----------------
__global__ void detect_dtype(const unsigned short* __restrict__ src, int* __restrict__ flag) {
    __shared__ int cnt;
    if (threadIdx.x == 0) cnt = 0;
    __syncthreads();
    int local = 0;
    for (int i = threadIdx.x; i < 16384; i += 256) {
        unsigned int e = (src[i] >> 7) & 0xFFu;
        if (e >= 143u) local++;
    }
    atomicAdd(&cnt, local);
    __syncthreads();
    if (threadIdx.x == 0) *flag = (cnt > 200) ? 1 : 0;
}

// ---------------- pack ----------------
__global__ void __launch_bounds__(256) pack_level(const void* __restrict__ src,
                                                  const void* __restrict__ pin,
                                                  const void* __restrict__ lemb, int lrow,
                                                  float* __restrict__ x,
                                                  bf16* __restrict__ pout,
                                                  int HW, int start,
                                                  const int* __restrict__ flag) {
    int isf32 = *flag;
    int i = blockIdx.x * 256 + threadIdx.x;
    int total = BATCH * HW * 256;
    if (i >= total) return;
    int c = i & 255;
    int t = i >> 8;
    int s = t % HW;
    int b = t / HW;
    size_t src_idx = ((size_t)b * 256 + c) * HW + s;
    float sv = ldin(src, src_idx, isf32);
    float pv = ldin(pin, src_idx, isf32) + ldin(lemb, (size_t)lrow * 256 + c, isf32);
    size_t o = ((size_t)b * S_TOT + start + s) * 256 + c;
    x[o] = sv;
    pout[o] = f2b(pv);
}

__global__ void __launch_bounds__(256) pack_task(const void* __restrict__ te,
                                                 const void* __restrict__ tpe,
                                                 float* __restrict__ x,
                                                 bf16* __restrict__ pout,
                                                 const int* __restrict__ flag) {
    int isf32 = *flag;
    int i = blockIdx.x * 256 + threadIdx.x;
    int total = BATCH * 20 * 256;
    if (i >= total) return;
    int c = i & 255;
    int t = (i >> 8) % 20;
    int b = (i >> 8) / 20;
    size_t o = ((size_t)b * S_TOT + 7581 + t) * 256 + c;
    x[o] = ldin(te, ((size_t)b * 20 + t) * 256 + c, isf32);
    pout[o] = f2b(ldin(tpe, (size_t)t * 256 + c, isf32));
}

__global__ void __launch_bounds__(256) make_ref(float* __restrict__ ref) {
    int s = blockIdx.x * 256 + threadIdx.x;
    if (s >= S_TOT) return;
    int H, W, st;
    if (s < 5776)      { H = 76; W = 76; st = 0; }
    else if (s < 7220) { H = 38; W = 38; st = 5776; }
    else if (s < 7581) { H = 19; W = 19; st = 7220; }
    else               { H = 1;  W = 20; st = 7581; }
    int r = s - st;
    int i = r / W, j = r % W;
    ref[s * 2 + 0] = (j + 0.5f) / (float)W;
    ref[s * 2 + 1] = (i + 0.5f) / (float)H;
}

__global__ void __launch_bounds__(256) cast_out(const float* __restrict__ x,
                                                void* __restrict__ o, int n,
                                                const int* __restrict__ flag) {
    int isf32 = *flag;
    int i = blockIdx.x * 256 + threadIdx.x;
    if (i >= n) return;
    if (isf32) ((float*)o)[i] = x[i];
    else       ((bf16*)o)[i] = f2b(x[i]);
}

// ---------------- cvt: xb = bf16(x), qb = bf16(x + pos) — single pass over x ----------------
__global__ void __launch_bounds__(256) cvt_xq(const float* __restrict__ x,
                                              const bf16* __restrict__ pos,
                                              bf16* __restrict__ xb,
                                              bf16* __restrict__ qb, int n4) {
    int i = blockIdx.x * 256 + threadIdx.x;
    if (i >= n4) return;
    float4 xv = ((const float4*)x)[i];
    ushort4 pv = ((const ushort4*)pos)[i];
    ushort4 xo, qo;
    xo.x = f2b(xv.x); xo.y = f2b(xv.y); xo.z = f2b(xv.z); xo.w = f2b(xv.w);
    qo.x = f2b(xv.x + b2f(pv.x));
    qo.y = f2b(xv.y + b2f(pv.y));
    qo.z = f2b(xv.z + b2f(pv.z));
    qo.w = f2b(xv.w + b2f(pv.w));
    ((ushort4*)xb)[i] = xo;
    ((ushort4*)qb)[i] = qo;
}

// ---------------- all-weights transpose: 1248 tiles of 32x32 per layer ----------------
// L0 >= 0: single layer L0, dst at base. L0 < 0: layer = blockIdx.y, dst offset by stride.
// Woff -> Wqt rows 0..255, Wa -> Wqt rows 256..383 (fused q-GEMM weight).
__global__ void __launch_bounds__(256) transpose_all(const void* __restrict__ Wv,
                                                     const void* __restrict__ Woff,
                                                     const void* __restrict__ Wa,
                                                     const void* __restrict__ Wo,
                                                     const void* __restrict__ W1,
                                                     const void* __restrict__ W2,
                                                     bf16* __restrict__ Wvt,
                                                     bf16* __restrict__ Wqt,
                                                     bf16* __restrict__ Wot,
                                                     bf16* __restrict__ W1t,
                                                     bf16* __restrict__ W2t,
                                                     int L0, const int* __restrict__ flag) {
    int isf32 = *flag;
    int L = (L0 >= 0) ? L0 : (int)blockIdx.y;
    size_t dl = (L0 >= 0) ? 0 : (size_t)blockIdx.y;
    int t = blockIdx.x;
    const void* src; bf16* dst; int K, N; size_t woff; int rowoff = 0;
    if (t < 64)        { src = Wv;   dst = Wvt + dl * 65536;  K = 256;  N = 256;  woff = (size_t)L * 65536; }
    else if (t < 128)  { src = Woff; dst = Wqt + dl * 98304;  K = 256;  N = 256;  woff = (size_t)L * 65536;  t -= 64; }
    else if (t < 160)  { src = Wa;   dst = Wqt + dl * 98304;  K = 256;  N = 128;  woff = (size_t)L * 32768;  rowoff = 256; t -= 128; }
    else if (t < 224)  { src = Wo;   dst = Wot + dl * 65536;  K = 256;  N = 256;  woff = (size_t)L * 65536;  t -= 160; }
    else if (t < 736)  { src = W1;   dst = W1t + dl * 524288; K = 256;  N = 2048; woff = (size_t)L * 524288; t -= 224; }
    else               { src = W2;   dst = W2t + dl * 524288; K = 2048; N = 256;  woff = (size_t)L * 524288; t -= 736; }
    int ntx = N >> 5;
    int tk = (t / ntx) * 32;
    int tn = (t % ntx) * 32;
    __shared__ float tl[32][33];
    int r = threadIdx.x >> 3;
    int c4 = (threadIdx.x & 7) * 4;
#pragma unroll
    for (int i = 0; i < 4; ++i)
        tl[r][c4 + i] = ldin(src, woff + (size_t)(tk + r) * N + tn + c4 + i, isf32);
    __syncthreads();
#pragma unroll
    for (int i = 0; i < 4; ++i)
        dst[(size_t)(tn + r + rowoff) * K + tk + c4 + i] = f2b(tl[c4 + i][r]);
}

// ---------------- MFMA GEMM 128x128, BK=64, global_load_lds staging (proven FFN1 config) ----------------
__global__ void __launch_bounds__(256) mfma_gemm(const bf16* __restrict__ A,
                                                 const bf16* __restrict__ Wt,
                                                 const void* __restrict__ bias, size_t boff,
                                                 bf16* __restrict__ C,
                                                 int M, int N, int K, int relu,
                                                 const int* __restrict__ flag) {
    int isf32 = *flag;
    __shared__ __align__(16) char smem[128 * 136 * 2];   // 34816 B: As+Bs (32768) / Cs overlay
    bf16* As = (bf16*)smem;               // [2][128][32]
    bf16* Bs = (bf16*)smem + 8192;        // [2][128][32]
    bf16* Cs = (bf16*)smem;               // 128 x 136 (16B-aligned rows)
    int tid = threadIdx.x;
    int lane = tid & 63, wave = tid >> 6;
    int wm = (wave & 1) << 6, wn = (wave >> 1) << 6;
    int bx, by;
    xcd_remap(bx, by);
    int bm = by * 128, bn = bx * 128;
    int q = lane >> 4, l15 = lane & 15;

    v4f acc[4][4];
#pragma unroll
    for (int i = 0; i < 4; ++i)
#pragma unroll
        for (int j = 0; j < 4; ++j) acc[i][j] = (v4f){0.f, 0.f, 0.f, 0.f};

    int r0 = tid >> 2, r1 = r0 + 64;
    int oct = (tid & 3) * 8;
    int am0 = bm + r0; if (am0 >= M) am0 = M - 1;
    int am1 = bm + r1; if (am1 >= M) am1 = M - 1;
    const bf16* ag0 = A + (size_t)am0 * K + oct;
    const bf16* ag1 = A + (size_t)am1 * K + oct;
    const bf16* bg0 = Wt + (size_t)(bn + r0) * K + oct;
    const bf16* bg1 = Wt + (size_t)(bn + r1) * K + oct;
    bf16* lA0 = As + tid * 8;
    bf16* lA1 = As + (tid + 256) * 8;
    bf16* lA2 = As + 4096 + tid * 8;
    bf16* lA3 = As + 4096 + (tid + 256) * 8;
    bf16* lB0 = Bs + tid * 8;
    bf16* lB1 = Bs + (tid + 256) * 8;
    bf16* lB2 = Bs + 4096 + tid * 8;
    bf16* lB3 = Bs + 4096 + (tid + 256) * 8;

    for (int k0 = 0; k0 < K; k0 += 64) {
        GLDS16(ag0 + k0, lA0);
        GLDS16(ag1 + k0, lA1);
        GLDS16(ag0 + k0 + 32, lA2);
        GLDS16(ag1 + k0 + 32, lA3);
        GLDS16(bg0 + k0, lB0);
        GLDS16(bg1 + k0, lB1);
        GLDS16(bg0 + k0 + 32, lB2);
        GLDS16(bg1 + k0 + 32, lB3);
        __syncthreads();
#pragma unroll
        for (int h = 0; h < 2; ++h) {
            v8s a_frag[4], b_frag[4];
#pragma unroll
            for (int mi = 0; mi < 4; ++mi)
                a_frag[mi] = *(const v8s*)&As[h * 4096 + (wm + mi * 16 + l15) * 32 + q * 8];
#pragma unroll
            for (int ni = 0; ni < 4; ++ni)
                b_frag[ni] = *(const v8s*)&Bs[h * 4096 + (wn + ni * 16 + l15) * 32 + q * 8];
#pragma unroll
            for (int mi = 0; mi < 4; ++mi)
#pragma unroll
                for (int ni = 0; ni < 4; ++ni)
                    acc[mi][ni] = __builtin_amdgcn_mfma_f32_16x16x32_bf16(
                        a_frag[mi], b_frag[ni], acc[mi][ni], 0, 0, 0);
        }
        __syncthreads();
    }

#pragma unroll
    for (int ni = 0; ni < 4; ++ni) {
        int cn = wn + ni * 16 + l15;
        float bv = ldin(bias, boff + bn + cn, isf32);
#pragma unroll
        for (int mi = 0; mi < 4; ++mi) {
#pragma unroll
            for (int r = 0; r < 4; ++r) {
                float v = acc[mi][ni][r] + bv;
                if (relu) v = fmaxf(v, 0.f);
                Cs[(wm + mi * 16 + q * 4 + r) * 136 + cn] = f2b(v);
            }
        }
    }
    __syncthreads();
    {
        int row = tid >> 1, half = tid & 1;
        int gm = bm + row;
        if (gm < M) {
            const bf16* srcp = Cs + row * 136 + half * 64;
            bf16* dstp = C + (size_t)gm * N + bn + half * 64;
#pragma unroll
            for (int i = 0; i < 8; ++i)
                *(uint4*)(dstp + i * 8) = *(const uint4*)(srcp + i * 8);
        }
    }
}

// ---------------- MFMA GEMM 64x64, BK=128: half the barrier count of BK=64 ----------------
// LDS 32KB (grid-limited occupancy ~3.7 blocks/CU < 5-block LDS capacity -> no occupancy loss).
// K=2048 (FFN2): 16 iters; K=256: 2 iters.
__global__ void __launch_bounds__(256) mfma_gemm64(const bf16* __restrict__ A,
                                                   const bf16* __restrict__ Wt,
                                                   const void* __restrict__ bias, size_t boff,
                                                   bf16* __restrict__ C,
                                                   int M, int N, int K, int relu,
                                                   const int* __restrict__ flag) {
    int isf32 = *flag;
    __shared__ __align__(16) char smem[32768];   // As [4][64][32] + Bs [4][64][32]; Cs overlay 9216
    bf16* As = (bf16*)smem;
    bf16* Bs = (bf16*)smem + 8192;
    bf16* Cs = (bf16*)smem;               // 64 x 72 (16B-aligned rows)
    int tid = threadIdx.x;
    int lane = tid & 63, wave = tid >> 6;
    int wm = (wave & 1) * 32, wn = (wave >> 1) * 32;
    int bx, by;
    xcd_remap(bx, by);
    int bm = by * 64, bn = bx * 64;
    int q = lane >> 4, l15 = lane & 15;

    v4f acc[2][2];
#pragma unroll
    for (int i = 0; i < 2; ++i)
#pragma unroll
        for (int j = 0; j < 2; ++j) acc[i][j] = (v4f){0.f, 0.f, 0.f, 0.f};

    int srow = tid >> 2;
    int oct = (tid & 3) * 8;
    int am = bm + srow; if (am >= M) am = M - 1;
    const bf16* arow = A + (size_t)am * K + oct;
    const bf16* brow = Wt + (size_t)(bn + srow) * K + oct;

    for (int k0 = 0; k0 < K; k0 += 128) {
#pragma unroll
        for (int h = 0; h < 4; ++h) {
            GLDS16(arow + k0 + h * 32, As + h * 2048 + tid * 8);
            GLDS16(brow + k0 + h * 32, Bs + h * 2048 + tid * 8);
        }
        __syncthreads();
#pragma unroll
        for (int h = 0; h < 4; ++h) {
            v8s a_frag[2], b_frag[2];
#pragma unroll
            for (int mi = 0; mi < 2; ++mi)
                a_frag[mi] = *(const v8s*)&As[h * 2048 + (wm + mi * 16 + l15) * 32 + q * 8];
#pragma unroll
            for (int ni = 0; ni < 2; ++ni)
                b_frag[ni] = *(const v8s*)&Bs[h * 2048 + (wn + ni * 16 + l15) * 32 + q * 8];
#pragma unroll
            for (int mi = 0; mi < 2; ++mi)
#pragma unroll
                for (int ni = 0; ni < 2; ++ni)
                    acc[mi][ni] = __builtin_amdgcn_mfma_f32_16x16x32_bf16(
                        a_frag[mi], b_frag[ni], acc[mi][ni], 0, 0, 0);
        }
        __syncthreads();
    }

#pragma unroll
    for (int ni = 0; ni < 2; ++ni) {
        int cn = wn + ni * 16 + l15;
        float bv = ldin(bias, boff + bn + cn, isf32);
#pragma unroll
        for (int mi = 0; mi < 2; ++mi) {
#pragma unroll
            for (int r = 0; r < 4; ++r) {
                float v = acc[mi][ni][r] + bv;
                if (relu) v = fmaxf(v, 0.f);
                Cs[(wm + mi * 16 + q * 4 + r) * 72 + cn] = f2b(v);
            }
        }
    }
    __syncthreads();
    {
        int row = tid >> 2, seg = tid & 3;
        int gm = bm + row;
        if (gm < M) {
            const bf16* srcp = Cs + row * 72 + seg * 16;
            bf16* dstp = C + (size_t)gm * N + bn + seg * 16;
            *(uint4*)(dstp) = *(const uint4*)(srcp);
            *(uint4*)(dstp + 8) = *(const uint4*)(srcp + 8);
        }
    }
}

// ---------------- fused value + q GEMM, one launch: grid (10, GM64), BK=128, K=256 ----------------
// bx<4 : value = xb @ Wvt (N=256 cols bx*64)
// bx>=4: [off|attn] = qb @ Wqt (N=384 cols (bx-4)*64); split epilogue off/attn.
__global__ void __launch_bounds__(256) mfma_gemm64_vq(const bf16* __restrict__ xb,
                                                      const bf16* __restrict__ qb,
                                                      const bf16* __restrict__ Wvt,
                                                      const bf16* __restrict__ Wqt,
                                                      const void* __restrict__ bv, size_t obv,
                                                      const void* __restrict__ bo, size_t obo,
                                                      const void* __restrict__ ba, size_t oba,
                                                      bf16* __restrict__ valueo,
                                                      bf16* __restrict__ offo,
                                                      bf16* __restrict__ attno,
                                                      int M, const int* __restrict__ flag) {
    const int K = 256;
    int isf32 = *flag;
    __shared__ __align__(16) char smem[32768];
    bf16* As = (bf16*)smem;
    bf16* Bs = (bf16*)smem + 8192;
    bf16* Cs = (bf16*)smem;
    int tid = threadIdx.x;
    int lane = tid & 63, wave = tid >> 6;
    int wm = (wave & 1) * 32, wn = (wave >> 1) * 32;
    int bx, by;
    xcd_remap(bx, by);
    int bm = by * 64;
    int isV = (bx < 4);
    int bn = isV ? bx * 64 : (bx - 4) * 64;     // value: 0..192; q: 0..320
    const bf16* A = isV ? xb : qb;
    const bf16* Wt = isV ? Wvt : Wqt;
    int q = lane >> 4, l15 = lane & 15;

    v4f acc[2][2];
#pragma unroll
    for (int i = 0; i < 2; ++i)
#pragma unroll
        for (int j = 0; j < 2; ++j) acc[i][j] = (v4f){0.f, 0.f, 0.f, 0.f};

    int srow = tid >> 2;
    int oct = (tid & 3) * 8;
    int am = bm + srow; if (am >= M) am = M - 1;
    const bf16* arow = A + (size_t)am * K + oct;
    const bf16* brow = Wt + (size_t)(bn + srow) * K + oct;

    for (int k0 = 0; k0 < K; k0 += 128) {
#pragma unroll
        for (int h = 0; h < 4; ++h) {
            GLDS16(arow + k0 + h * 32, As + h * 2048 + tid * 8);
            GLDS16(brow + k0 + h * 32, Bs + h * 2048 + tid * 8);
        }
        __syncthreads();
#pragma unroll
        for (int h = 0; h < 4; ++h) {
            v8s a_frag[2], b_frag[2];
#pragma unroll
            for (int mi = 0; mi < 2; ++mi)
                a_frag[mi] = *(const v8s*)&As[h * 2048 + (wm + mi * 16 + l15) * 32 + q * 8];
#pragma unroll
            for (int ni = 0; ni < 2; ++ni)
                b_frag[ni] = *(const v8s*)&Bs[h * 2048 + (wn + ni * 16 + l15) * 32 + q * 8];
#pragma unroll
            for (int mi = 0; mi < 2; ++mi)
#pragma unroll
                for (int ni = 0; ni < 2; ++ni)
                    acc[mi][ni] = __builtin_amdgcn_mfma_f32_16x16x32_bf16(
                        a_frag[mi], b_frag[ni], acc[mi][ni], 0, 0, 0);
        }
        __syncthreads();
    }

    // block-uniform output routing
    bf16* outp; int outN, colbase; const void* bptr; size_t bofs;
    if (isV)             { outp = valueo; outN = 256; colbase = bn;       bptr = bv; bofs = obv; }
    else if (bn < 256)   { outp = offo;   outN = 256; colbase = bn;       bptr = bo; bofs = obo; }
    else                 { outp = attno;  outN = 128; colbase = bn - 256; bptr = ba; bofs = oba; }

#pragma unroll
    for (int ni = 0; ni < 2; ++ni) {
        int cn = wn + ni * 16 + l15;
        float bvf = ldin(bptr, bofs + colbase + cn, isf32);
#pragma unroll
        for (int mi = 0; mi < 2; ++mi) {
#pragma unroll
            for (int r = 0; r < 4; ++r) {
                Cs[(wm + mi * 16 + q * 4 + r) * 72 + cn] = f2b(acc[mi][ni][r] + bvf);
            }
        }
    }
    __syncthreads();
    {
        int row = tid >> 2, seg = tid & 3;
        int gm = bm + row;
        if (gm < M) {
            const bf16* srcp = Cs + row * 72 + seg * 16;
            bf16* dstp = outp + (size_t)gm * outN + colbase + seg * 16;
            *(uint4*)(dstp) = *(const uint4*)(srcp);
            *(uint4*)(dstp + 8) = *(const uint4*)(srcp + 8);
        }
    }
}

// ---------------- fallback VALU GEMM ----------------
template<typename TA, int ADDPOS, int RELU>
__global__ void __launch_bounds__(256) gemm_bias(const TA* __restrict__ A,
                                                 const bf16* __restrict__ Apos,
                                                 const void* __restrict__ W, size_t woff,
                                                 const void* __restrict__ bias, size_t boff,
                                                 bf16* __restrict__ C,
                                                 int M, int N, int K,
                                                 const int* __restrict__ flag) {
    int isf32 = *flag;
    __shared__ float As[16][65];
    __shared__ float Bs[16][65];
    int tid = threadIdx.x;
    int tx = tid & 15;
    int ty = tid >> 4;
    int bm = blockIdx.y * 64;
    int bn = blockIdx.x * 64;
    float acc[4][4] = {};
    for (int k0 = 0; k0 < K; k0 += 16) {
#pragma unroll
        for (int e = 0; e < 4; ++e) {
            int idx = tid + e * 256;
            int mm = idx >> 4;
            int kk = idx & 15;
            int gm = bm + mm;
            float av = 0.f;
            if (gm < M) {
                size_t ai = (size_t)gm * K + k0 + kk;
                if (sizeof(TA) == 4) av = ((const float*)A)[ai];
                else                 av = b2f(((const bf16*)A)[ai]);
                if (ADDPOS) av += b2f(Apos[ai]);
            }
            As[kk][mm] = av;
        }
#pragma unroll
        for (int e = 0; e < 4; ++e) {
            int idx = tid + e * 256;
            int kk = idx >> 6;
            int nn = idx & 63;
            int gn = bn + nn;
            Bs[kk][nn] = (gn < N) ? ldin(W, woff + (size_t)(k0 + kk) * N + gn, isf32) : 0.f;
        }
        __syncthreads();
#pragma unroll
        for (int kk = 0; kk < 16; ++kk) {
            float a[4], b[4];
#pragma unroll
            for (int i = 0; i < 4; ++i) a[i] = As[kk][ty + 16 * i];
#pragma unroll
            for (int j = 0; j < 4; ++j) b[j] = Bs[kk][tx + 16 * j];
#pragma unroll
            for (int i = 0; i < 4; ++i)
#pragma unroll
                for (int j = 0; j < 4; ++j) acc[i][j] += a[i] * b[j];
        }
        __syncthreads();
    }
#pragma unroll
    for (int i = 0; i < 4; ++i) {
        int gm = bm + ty + 16 * i;
        if (gm >= M) continue;
#pragma unroll
        for (int j = 0; j < 4; ++j) {
            int gn = bn + tx + 16 * j;
            if (gn >= N) continue;
            float v = acc[i][j] + ldin(bias, boff + gn, isf32);
            if (RELU) v = fmaxf(v, 0.f);
            C[(size_t)gm * N + gn] = f2b(v);
        }
    }
}

// ---------------- MS-deform sampling: 4 rows/block, wave-parallel softmax ----------------
__global__ void __launch_bounds__(256) msdeform_sample4(const bf16* __restrict__ value,
                                                        const bf16* __restrict__ off,
                                                        const bf16* __restrict__ logits,
                                                        const float* __restrict__ refpts,
                                                        bf16* __restrict__ out) {
    __shared__ float sAttn[4 * 128];
    __shared__ int2 sIW[4 * 520];
    const int LH[4] = {76, 38, 19, 1};
    const int LW[4] = {76, 38, 19, 20};
    const int LS[4] = {0, 5776, 7220, 7581};
    int tid = threadIdx.x;
    int m0 = blockIdx.x * 4;

    for (int i = tid; i < 4 * 128; i += 256) {
        int r = i >> 7, li = i & 127;
        int m = m0 + r;
        int mc = (m < BM) ? m : BM - 1;
        sAttn[i] = b2f(logits[(size_t)mc * 128 + li]);
    }
    __syncthreads();
    {
        // 32 groups (4 rows x 8 heads) x 16 logits; 8 threads/group, 2 elems/thread.
        // Groups are 8 consecutive lanes -> shfl_xor(1,2,4) stays in-group.
        int g = tid >> 3, j = tid & 7;
        float* gp = sAttn + g * 16;
        float e0 = gp[j * 2], e1 = gp[j * 2 + 1];
        float mx = fmaxf(e0, e1);
#pragma unroll
        for (int o = 1; o < 8; o <<= 1) mx = fmaxf(mx, __shfl_xor(mx, o));
        e0 = __expf(e0 - mx);
        e1 = __expf(e1 - mx);
        float sm = e0 + e1;
#pragma unroll
        for (int o = 1; o < 8; o <<= 1) sm += __shfl_xor(sm, o);
        float inv = 1.f / sm;
        gp[j * 2] = e0 * inv;
        gp[j * 2 + 1] = e1 * inv;
    }
    __syncthreads();
    for (int i = tid; i < 4 * 128; i += 256) {
        int r = i >> 7, oi = i & 127;
        int m = m0 + r;
        int mc = (m < BM) ? m : BM - 1;
        int b = mc / S_TOT;
        int s = mc - b * S_TOT;
        int h = oi >> 4;
        int l = (oi >> 2) & 3;
        int H = LH[l], W = LW[l], st = LS[l];
        float fW = (float)W, fH = (float)H;
        float refx = refpts[s * 2 + 0];
        float refy = refpts[s * 2 + 1];
        ushort2 ov = *(const ushort2*)(off + (size_t)mc * 256 + oi * 2);
        float a = sAttn[r * 128 + oi];
        float xpix = (refx + b2f(ov.x) / fW) * fW - 0.5f;
        float ypix = (refy + b2f(ov.y) / fH) * fH - 0.5f;
        float x0f = floorf(xpix), y0f = floorf(ypix);
        int x0 = (int)x0f, y0 = (int)y0f;
        float wx1 = xpix - x0f, wy1 = ypix - y0f;
        float wx0 = 1.f - wx1, wy0 = 1.f - wy1;
        int vb = b * (S_TOT * 256) + h * 32;
        int base = r * 520 + h * 65 + (oi & 15) * 4;
#pragma unroll
        for (int c = 0; c < 4; ++c) {
            int cx = c & 1, cy = c >> 1;
            int xi = x0 + cx, yi = y0 + cy;
            float w = (cx ? wx1 : wx0) * (cy ? wy1 : wy0) * a;
            bool valid = (xi >= 0) && (xi <= W - 1) && (yi >= 0) && (yi <= H - 1);
            int xic = min(max(xi, 0), W - 1), yic = min(max(yi, 0), H - 1);
            int2 d;
            d.x = vb + (st + yic * W + xic) * 256;
            d.y = __float_as_int(valid ? w : 0.f);
            sIW[base + c] = d;
        }
    }
    __syncthreads();
    int r = tid >> 6, u = tid & 63;
    int h = u >> 3, d4 = (u & 7) * 4;
    int m = m0 + r;
    int cb = r * 520 + h * 65;
    float acc0 = 0.f, acc1 = 0.f, acc2 = 0.f, acc3 = 0.f;
#pragma unroll 8
    for (int c = 0; c < 64; ++c) {
        int2 p = sIW[cb + c];
        float w = __int_as_float(p.y);
        ushort4 v = *(const ushort4*)(value + p.x + d4);
        acc0 += w * b2f(v.x);
        acc1 += w * b2f(v.y);
        acc2 += w * b2f(v.z);
        acc3 += w * b2f(v.w);
    }
    if (m < BM) {
        ushort4 o;
        o.x = f2b(acc0); o.y = f2b(acc1); o.z = f2b(acc2); o.w = f2b(acc3);
        *(ushort4*)(out + (size_t)m * 256 + h * 32 + d4) = o;
    }
}

// ---------------- residual + LayerNorm: 4 rows/block, 1 wave/row; optional xb and qb=bf16(x+pos) ----------------
__global__ void __launch_bounds__(256) residual_ln4(float* __restrict__ x,
                                                    const bf16* __restrict__ y,
                                                    const void* __restrict__ g, size_t goff,
                                                    const void* __restrict__ beta, size_t boff,
                                                    const int* __restrict__ flag,
                                                    bf16* __restrict__ xb,
                                                    const bf16* __restrict__ pos,
                                                    bf16* __restrict__ qb) {
    int isf32 = *flag;
    int tid = threadIdx.x;
    int r = tid >> 6, lane = tid & 63;
    int m = blockIdx.x * 4 + r;
    if (m >= BM) return;
    size_t o = (size_t)m * 256 + lane * 4;
    float4 xv = *(const float4*)(x + o);
    ushort4 yv = *(const ushort4*)(y + o);
    float r0 = xv.x + b2f(yv.x), r1 = xv.y + b2f(yv.y);
    float r2 = xv.z + b2f(yv.z), r3 = xv.w + b2f(yv.w);
    float sum = r0 + r1 + r2 + r3;
#pragma unroll
    for (int ofs = 32; ofs > 0; ofs >>= 1) sum += __shfl_xor(sum, ofs);
    float mean = sum * (1.f / 256.f);
    float d0 = r0 - mean, d1 = r1 - mean, d2 = r2 - mean, d3 = r3 - mean;
    float vv = d0 * d0 + d1 * d1 + d2 * d2 + d3 * d3;
#pragma unroll
    for (int ofs = 32; ofs > 0; ofs >>= 1) vv += __shfl_xor(vv, ofs);
    float rstd = rsqrtf(vv * (1.f / 256.f) + 1e-5f);
    int c = lane * 4;
    float o0 = d0 * rstd * ldin(g, goff + c + 0, isf32) + ldin(beta, boff + c + 0, isf32);
    float o1 = d1 * rstd * ldin(g, goff + c + 1, isf32) + ldin(beta, boff + c + 1, isf32);
    float o2 = d2 * rstd * ldin(g, goff + c + 2, isf32) + ldin(beta, boff + c + 2, isf32);
    float o3 = d3 * rstd * ldin(g, goff + c + 3, isf32) + ldin(beta, boff + c + 3, isf32);
    *(float4*)(x + o) = make_float4(o0, o1, o2, o3);
    if (xb) {
        ushort4 xo;
        xo.x = f2b(o0); xo.y = f2b(o1); xo.z = f2b(o2); xo.w = f2b(o3);
        *(ushort4*)(xb + o) = xo;
    }
    if (qb) {
        ushort4 pv = *(const ushort4*)(pos + o);
        ushort4 qo;
        qo.x = f2b(o0 + b2f(pv.x));
        qo.y = f2b(o1 + b2f(pv.y));
        qo.z = f2b(o2 + b2f(pv.z));
        qo.w = f2b(o3 + b2f(pv.w));
        *(ushort4*)(qb + o) = qo;
    }
}

// ---------------- host ----------------
extern "C" void kernel_launch(void* const* d_in, const int* in_sizes, int n_in,
                              void* d_out, int out_size, void* d_ws, size_t ws_size,
                              hipStream_t stream) {
    (void)in_sizes; (void)n_in; (void)out_size;
    const size_t MS = (size_t)BM * DMODEL;   // 3,891,712

    char* base = (char*)d_ws;
    int* flag    = (int*)base;    base += 256;
    float* x     = (float*)base;  base += MS * 4;
    bf16* value  = (bf16*)base;   base += MS * 2;
    bf16* attnl  = (bf16*)base;   base += (size_t)BM * 128 * 2;
    bf16* pos    = (bf16*)base;   base += MS * 2;
    bf16* offms  = (bf16*)base;   base += MS * 2;   // off -> msout in place
    bf16* yb     = (bf16*)base;   base += MS * 2;   // also qb (dead before Wo writes)
    size_t base_used = (size_t)(base - (char*)d_ws);

    // transposed-weight element counts per layer
    const size_t SZ_WVT = 65536, SZ_WQT = 98304, SZ_WOT = 65536, SZ_W1T = 524288, SZ_W2T = 524288;
    const size_t WB1 = (SZ_WVT + SZ_WQT + SZ_WOT + SZ_W1T + SZ_W2T) * 2;   // bytes per layer

    bf16* xb = (bf16*)base;
    size_t needB  = base_used + MS * 2 + WB1 + (size_t)S_TOT * 8 + 1024;
    size_t needAH = ((base_used + MS * 2 + 6 * WB1 + (size_t)S_TOT * 8 + 1024 + 255) & ~(size_t)255)
                  + (size_t)BM * 2048 * 2;
    bool FAST = ws_size >= needB;
    bool W6   = ws_size >= needAH;      // 6-layer weights + full hidden
    int  nL   = W6 ? 6 : 1;

    bf16 *W1t = nullptr, *W2t = nullptr, *Wvt = nullptr, *Wqt = nullptr, *Wot = nullptr;
    float* ref;
    bf16* hiddenF = nullptr;
    bool FULLH = false;
    if (FAST) {
        char* p = (char*)xb + MS * 2;
        Wvt = (bf16*)p;  p += (size_t)nL * SZ_WVT * 2;
        Wqt = (bf16*)p;  p += (size_t)nL * SZ_WQT * 2;
        Wot = (bf16*)p;  p += (size_t)nL * SZ_WOT * 2;
        W1t = (bf16*)p;  p += (size_t)nL * SZ_W1T * 2;
        W2t = (bf16*)p;  p += (size_t)nL * SZ_W2T * 2;
        ref = (float*)p; p += (size_t)S_TOT * 2 * 4;
        size_t used = (size_t)(p - (char*)d_ws);
        used = (used + 255) & ~(size_t)255;
        if (ws_size >= used + (size_t)BM * 2048 * 2) {
            hiddenF = (bf16*)((char*)d_ws + used);
            FULLH = true;
        }
    } else {
        ref = (float*)base;
    }

    bf16* hidden = FULLH ? hiddenF : value;
    const int CH = FULLH ? BM : 2816;

    detect_dtype<<<1, 256, 0, stream>>>((const unsigned short*)d_in[0], flag);

    {
        int HW0 = 76 * 76, HW1 = 38 * 38, HW2 = 19 * 19;
        int n0 = BATCH * HW0 * 256, n1 = BATCH * HW1 * 256, n2 = BATCH * HW2 * 256;
        pack_level<<<(n0 + 255) / 256, 256, 0, stream>>>(d_in[0], d_in[1], d_in[8], 0, x, pos, HW0, 0, flag);
        pack_level<<<(n1 + 255) / 256, 256, 0, stream>>>(d_in[2], d_in[3], d_in[8], 1, x, pos, HW1, 5776, flag);
        pack_level<<<(n2 + 255) / 256, 256, 0, stream>>>(d_in[4], d_in[5], d_in[8], 2, x, pos, HW2, 7220, flag);
        int nt = BATCH * 20 * 256;
        pack_task<<<(nt + 255) / 256, 256, 0, stream>>>(d_in[6], d_in[7], x, pos, flag);
        make_ref<<<(S_TOT + 255) / 256, 256, 0, stream>>>(ref);
    }

    const int GM64 = (BM + 63) / 64;      // 238
    const int GR4 = (BM + 3) / 4;         // 3801
    const int n4 = (int)(MS / 4);

    if (FAST) {
        cvt_xq<<<(n4 + 255) / 256, 256, 0, stream>>>(x, pos, xb, yb, n4);   // xb + qb (layer 0)
        if (W6) {   // all 6 layers' weight transposes upfront, one launch
            transpose_all<<<dim3(1248, 6), 256, 0, stream>>>(d_in[13], d_in[9], d_in[11], d_in[15],
                                                             d_in[17], d_in[19],
                                                             Wvt, Wqt, Wot, W1t, W2t, -1, flag);
        }
    }

    for (int L = 0; L < 6; ++L) {
        size_t oW256 = (size_t)L * 256 * 256, ob256 = (size_t)L * 256;
        size_t oW128 = (size_t)L * 256 * 128, ob128 = (size_t)L * 128;
        size_t oW1   = (size_t)L * 256 * 2048, ob1  = (size_t)L * 2048;
        size_t oW2   = (size_t)L * 2048 * 256;

        if (FAST) {
            bf16* WvtL = Wvt + (W6 ? (size_t)L * SZ_WVT : 0);
            bf16* WqtL = Wqt + (W6 ? (size_t)L * SZ_WQT : 0);
            bf16* WotL = Wot + (W6 ? (size_t)L * SZ_WOT : 0);
            bf16* W1tL = W1t + (W6 ? (size_t)L * SZ_W1T : 0);
            bf16* W2tL = W2t + (W6 ? (size_t)L * SZ_W2T : 0);
            if (!W6) {
                transpose_all<<<dim3(1248, 1), 256, 0, stream>>>(d_in[13], d_in[9], d_in[11], d_in[15],
                                                                 d_in[17], d_in[19],
                                                                 Wvt, Wqt, Wot, W1t, W2t, L, flag);
            }
            bf16* qb = yb;
            mfma_gemm64_vq<<<dim3(10, GM64), 256, 0, stream>>>(xb, qb, WvtL, WqtL,
                                                               d_in[14], ob256, d_in[10], ob256,
                                                               d_in[12], ob128,
                                                               value, offms, attnl, BM, flag);

            msdeform_sample4<<<GR4, 256, 0, stream>>>(value, offms, attnl, ref, offms);

            mfma_gemm64<<<dim3(4, GM64), 256, 0, stream>>>(offms, WotL, d_in[16], ob256, yb, BM, 256, 256, 0, flag);
            residual_ln4<<<GR4, 256, 0, stream>>>(x, yb, d_in[21], ob256, d_in[22], ob256, flag, xb, nullptr, nullptr);

            for (int r0 = 0; r0 < BM; r0 += CH) {
                int mc = BM - r0 < CH ? BM - r0 : CH;
                int gmc128 = (mc + 127) / 128;
                int gmc64 = (mc + 63) / 64;
                mfma_gemm<<<dim3(16, gmc128), 256, 0, stream>>>(xb + (size_t)r0 * 256, W1tL, d_in[18], ob1,
                                                                hidden, mc, 2048, 256, 1, flag);
                mfma_gemm64<<<dim3(4, gmc64), 256, 0, stream>>>(hidden, W2tL, d_in[20], ob256,
                                                                yb + (size_t)r0 * 256, mc, 256, 2048, 0, flag);
            }
            residual_ln4<<<GR4, 256, 0, stream>>>(x, yb, d_in[23], ob256, d_in[24], ob256, flag, xb,
                                                  (L < 5) ? pos : nullptr, (L < 5) ? yb : nullptr);
        } else {
            dim3 g256(4, GM64);
            dim3 g128(2, GM64);
            gemm_bias<float, 0, 0><<<g256, 256, 0, stream>>>(x, nullptr, d_in[13], oW256, d_in[14], ob256,
                                                             value, BM, 256, 256, flag);
            gemm_bias<float, 1, 0><<<g256, 256, 0, stream>>>(x, pos, d_in[9], oW256, d_in[10], ob256,
                                                             offms, BM, 256, 256, flag);
            gemm_bias<float, 1, 0><<<g128, 256, 0, stream>>>(x, pos, d_in[11], oW128, d_in[12], ob128,
                                                             attnl, BM, 128, 256, flag);
            msdeform_sample4<<<GR4, 256, 0, stream>>>(value, offms, attnl, ref, offms);
            gemm_bias<bf16, 0, 0><<<g256, 256, 0, stream>>>(offms, nullptr, d_in[15], oW256, d_in[16], ob256,
                                                            yb, BM, 256, 256, flag);
            residual_ln4<<<GR4, 256, 0, stream>>>(x, yb, d_in[21], ob256, d_in[22], ob256, flag, nullptr, nullptr, nullptr);
            for (int r0 = 0; r0 < BM; r0 += CH) {
                int mc = BM - r0 < CH ? BM - r0 : CH;
                dim3 gh(32, (mc + 63) / 64);
                dim3 go(4, (mc + 63) / 64);
                gemm_bias<float, 0, 1><<<gh, 256, 0, stream>>>(x + (size_t)r0 * 256, nullptr, d_in[17], oW1,
                                                               d_in[18], ob1, hidden, mc, 2048, 256, flag);
                gemm_bias<bf16, 0, 0><<<go, 256, 0, stream>>>(hidden, nullptr, d_in[19], oW2, d_in[20], ob256,
                                                              yb + (size_t)r0 * 256, mc, 256, 2048, flag);
            }
            residual_ln4<<<GR4, 256, 0, stream>>>(x, yb, d_in[23], ob256, d_in[24], ob256, flag, nullptr, nullptr, nullptr);
        }
    }

    cast_out<<<((int)MS + 255) / 256, 256, 0, stream>>>(x, d_out, (int)MS, flag);
}

// Round 7
// 1135.304 us; speedup vs baseline: 1.0593x; 1.0593x over previous
//
#include <hip/hip_runtime.h>

#define S_TOT 7601
#define BATCH 2
#define BM (BATCH * S_TOT)   // 15202
#define DMODEL 256

typedef unsigned short bf16;
typedef __attribute__((ext_vector_type(8))) short v8s;
typedef __attribute__((ext_vector_type(4))) float v4f;

__device__ __forceinline__ float b2f(bf16 u) {
    union { unsigned int i; float f; } v;
    v.i = ((unsigned int)u) << 16;
    return v.f;
}
__device__ __forceinline__ bf16 f2b(float f) {
    union { unsigned int i; float f; } v;
    v.f = f;
    unsigned int r = v.i + 0x7FFFu + ((v.i >> 16) & 1u);
    return (bf16)(r >> 16);
}
__device__ __forceinline__ float ldin(const void* p, size_t i, int isf32) {
    return isf32 ? ((const float*)p)[i] : b2f(((const bf16*)p)[i]);
}

// async global->LDS, 16B per lane. LDS dest must be linear: wave-uniform base + lane*16.
#define GLDS16(gp, lp)                                                          \
    __builtin_amdgcn_global_load_lds(                                           \
        (const __attribute__((address_space(1))) unsigned int*)(gp),            \
        (__attribute__((address_space(3))) unsigned int*)(lp), 16, 0, 0)

// bijective XCD-chunked block remap (m204): consecutive logical blocks land on one XCD.
__device__ __forceinline__ void xcd_remap(int& bx, int& by) {
    int gx = gridDim.x, gy = gridDim.y;
    int nwg = gx * gy;
    int lin = blockIdx.y * gx + blockIdx.x;
    int q = nwg >> 3, r = nwg & 7;
    int xcd = lin & 7, idx = lin >> 3;
    int lin2 = (xcd < r ? xcd * (q + 1) : r * (q + 1) + (xcd - r) * q) + idx;
    bx = lin2 % gx;
    by = lin2 / gx;
}

// ---------------- dtype probe ----------------
__global__ void detect_dtype(const unsigned short* __restrict__ src, int* __restrict__ flag) {
    __shared__ int cnt;
    if (threadIdx.x == 0) cnt = 0;
    __syncthreads();
    int local = 0;
    for (int i = threadIdx.x; i < 16384; i += 256) {
        unsigned int e = (src[i] >> 7) & 0xFFu;
        if (e >= 143u) local++;
    }
    atomicAdd(&cnt, local);
    __syncthreads();
    if (threadIdx.x == 0) *flag = (cnt > 200) ? 1 : 0;
}

// ---------------- pack ----------------
__global__ void __launch_bounds__(256) pack_level(const void* __restrict__ src,
                                                  const void* __restrict__ pin,
                                                  const void* __restrict__ lemb, int lrow,
                                                  float* __restrict__ x,
                                                  bf16* __restrict__ pout,
                                                  int HW, int start,
                                                  const int* __restrict__ flag) {
    int isf32 = *flag;
    int i = blockIdx.x * 256 + threadIdx.x;
    int total = BATCH * HW * 256;
    if (i >= total) return;
    int c = i & 255;
    int t = i >> 8;
    int s = t % HW;
    int b = t / HW;
    size_t src_idx = ((size_t)b * 256 + c) * HW + s;
    float sv = ldin(src, src_idx, isf32);
    float pv = ldin(pin, src_idx, isf32) + ldin(lemb, (size_t)lrow * 256 + c, isf32);
    size_t o = ((size_t)b * S_TOT + start + s) * 256 + c;
    x[o] = sv;
    pout[o] = f2b(pv);
}

__global__ void __launch_bounds__(256) pack_task(const void* __restrict__ te,
                                                 const void* __restrict__ tpe,
                                                 float* __restrict__ x,
                                                 bf16* __restrict__ pout,
                                                 const int* __restrict__ flag) {
    int isf32 = *flag;
    int i = blockIdx.x * 256 + threadIdx.x;
    int total = BATCH * 20 * 256;
    if (i >= total) return;
    int c = i & 255;
    int t = (i >> 8) % 20;
    int b = (i >> 8) / 20;
    size_t o = ((size_t)b * S_TOT + 7581 + t) * 256 + c;
    x[o] = ldin(te, ((size_t)b * 20 + t) * 256 + c, isf32);
    pout[o] = f2b(ldin(tpe, (size_t)t * 256 + c, isf32));
}

__global__ void __launch_bounds__(256) make_ref(float* __restrict__ ref) {
    int s = blockIdx.x * 256 + threadIdx.x;
    if (s >= S_TOT) return;
    int H, W, st;
    if (s < 5776)      { H = 76; W = 76; st = 0; }
    else if (s < 7220) { H = 38; W = 38; st = 5776; }
    else if (s < 7581) { H = 19; W = 19; st = 7220; }
    else               { H = 1;  W = 20; st = 7581; }
    int r = s - st;
    int i = r / W, j = r % W;
    ref[s * 2 + 0] = (j + 0.5f) / (float)W;
    ref[s * 2 + 1] = (i + 0.5f) / (float)H;
}

__global__ void __launch_bounds__(256) cast_out(const float* __restrict__ x,
                                                void* __restrict__ o, int n,
                                                const int* __restrict__ flag) {
    int isf32 = *flag;
    int i = blockIdx.x * 256 + threadIdx.x;
    if (i >= n) return;
    if (isf32) ((float*)o)[i] = x[i];
    else       ((bf16*)o)[i] = f2b(x[i]);
}

// ---------------- cvt: xb = bf16(x), qb = bf16(x + pos) — single pass over x ----------------
__global__ void __launch_bounds__(256) cvt_xq(const float* __restrict__ x,
                                              const bf16* __restrict__ pos,
                                              bf16* __restrict__ xb,
                                              bf16* __restrict__ qb, int n4) {
    int i = blockIdx.x * 256 + threadIdx.x;
    if (i >= n4) return;
    float4 xv = ((const float4*)x)[i];
    ushort4 pv = ((const ushort4*)pos)[i];
    ushort4 xo, qo;
    xo.x = f2b(xv.x); xo.y = f2b(xv.y); xo.z = f2b(xv.z); xo.w = f2b(xv.w);
    qo.x = f2b(xv.x + b2f(pv.x));
    qo.y = f2b(xv.y + b2f(pv.y));
    qo.z = f2b(xv.z + b2f(pv.z));
    qo.w = f2b(xv.w + b2f(pv.w));
    ((ushort4*)xb)[i] = xo;
    ((ushort4*)qb)[i] = qo;
}

// ---------------- all-weights transpose: 1248 tiles of 32x32 per layer ----------------
// L0 >= 0: single layer L0, dst at base. L0 < 0: layer = blockIdx.y, dst offset by stride.
// Woff -> Wqt rows 0..255, Wa -> Wqt rows 256..383 (fused q-GEMM weight).
__global__ void __launch_bounds__(256) transpose_all(const void* __restrict__ Wv,
                                                     const void* __restrict__ Woff,
                                                     const void* __restrict__ Wa,
                                                     const void* __restrict__ Wo,
                                                     const void* __restrict__ W1,
                                                     const void* __restrict__ W2,
                                                     bf16* __restrict__ Wvt,
                                                     bf16* __restrict__ Wqt,
                                                     bf16* __restrict__ Wot,
                                                     bf16* __restrict__ W1t,
                                                     bf16* __restrict__ W2t,
                                                     int L0, const int* __restrict__ flag) {
    int isf32 = *flag;
    int L = (L0 >= 0) ? L0 : (int)blockIdx.y;
    size_t dl = (L0 >= 0) ? 0 : (size_t)blockIdx.y;
    int t = blockIdx.x;
    const void* src; bf16* dst; int K, N; size_t woff; int rowoff = 0;
    if (t < 64)        { src = Wv;   dst = Wvt + dl * 65536;  K = 256;  N = 256;  woff = (size_t)L * 65536; }
    else if (t < 128)  { src = Woff; dst = Wqt + dl * 98304;  K = 256;  N = 256;  woff = (size_t)L * 65536;  t -= 64; }
    else if (t < 160)  { src = Wa;   dst = Wqt + dl * 98304;  K = 256;  N = 128;  woff = (size_t)L * 32768;  rowoff = 256; t -= 128; }
    else if (t < 224)  { src = Wo;   dst = Wot + dl * 65536;  K = 256;  N = 256;  woff = (size_t)L * 65536;  t -= 160; }
    else if (t < 736)  { src = W1;   dst = W1t + dl * 524288; K = 256;  N = 2048; woff = (size_t)L * 524288; t -= 224; }
    else               { src = W2;   dst = W2t + dl * 524288; K = 2048; N = 256;  woff = (size_t)L * 524288; t -= 736; }
    int ntx = N >> 5;
    int tk = (t / ntx) * 32;
    int tn = (t % ntx) * 32;
    __shared__ float tl[32][33];
    int r = threadIdx.x >> 3;
    int c4 = (threadIdx.x & 7) * 4;
#pragma unroll
    for (int i = 0; i < 4; ++i)
        tl[r][c4 + i] = ldin(src, woff + (size_t)(tk + r) * N + tn + c4 + i, isf32);
    __syncthreads();
#pragma unroll
    for (int i = 0; i < 4; ++i)
        dst[(size_t)(tn + r + rowoff) * K + tk + c4 + i] = f2b(tl[c4 + i][r]);
}

// ---------------- MFMA GEMM 128x128, BK=64, direct-store epilogue ----------------
// Dropping the Cs LDS overlay (was 34816B) -> LDS 32768 -> 5 blocks/CU (+25% capacity),
// and removes 2 barriers + LDS round-trip. Stores: 16-lane x 2B = 32B segments; adjacent
// ni segments of the same row are issued back-to-back -> L2 write-combines to full lines.
__global__ void __launch_bounds__(256) mfma_gemm(const bf16* __restrict__ A,
                                                 const bf16* __restrict__ Wt,
                                                 const void* __restrict__ bias, size_t boff,
                                                 bf16* __restrict__ C,
                                                 int M, int N, int K, int relu,
                                                 const int* __restrict__ flag) {
    int isf32 = *flag;
    __shared__ __align__(16) char smem[32768];   // As+Bs only
    bf16* As = (bf16*)smem;               // [2][128][32]
    bf16* Bs = (bf16*)smem + 8192;        // [2][128][32]
    int tid = threadIdx.x;
    int lane = tid & 63, wave = tid >> 6;
    int wm = (wave & 1) << 6, wn = (wave >> 1) << 6;
    int bx, by;
    xcd_remap(bx, by);
    int bm = by * 128, bn = bx * 128;
    int q = lane >> 4, l15 = lane & 15;

    v4f acc[4][4];
#pragma unroll
    for (int i = 0; i < 4; ++i)
#pragma unroll
        for (int j = 0; j < 4; ++j) acc[i][j] = (v4f){0.f, 0.f, 0.f, 0.f};

    int r0 = tid >> 2, r1 = r0 + 64;
    int oct = (tid & 3) * 8;
    int am0 = bm + r0; if (am0 >= M) am0 = M - 1;
    int am1 = bm + r1; if (am1 >= M) am1 = M - 1;
    const bf16* ag0 = A + (size_t)am0 * K + oct;
    const bf16* ag1 = A + (size_t)am1 * K + oct;
    const bf16* bg0 = Wt + (size_t)(bn + r0) * K + oct;
    const bf16* bg1 = Wt + (size_t)(bn + r1) * K + oct;
    bf16* lA0 = As + tid * 8;
    bf16* lA1 = As + (tid + 256) * 8;
    bf16* lA2 = As + 4096 + tid * 8;
    bf16* lA3 = As + 4096 + (tid + 256) * 8;
    bf16* lB0 = Bs + tid * 8;
    bf16* lB1 = Bs + (tid + 256) * 8;
    bf16* lB2 = Bs + 4096 + tid * 8;
    bf16* lB3 = Bs + 4096 + (tid + 256) * 8;

    for (int k0 = 0; k0 < K; k0 += 64) {
        GLDS16(ag0 + k0, lA0);
        GLDS16(ag1 + k0, lA1);
        GLDS16(ag0 + k0 + 32, lA2);
        GLDS16(ag1 + k0 + 32, lA3);
        GLDS16(bg0 + k0, lB0);
        GLDS16(bg1 + k0, lB1);
        GLDS16(bg0 + k0 + 32, lB2);
        GLDS16(bg1 + k0 + 32, lB3);
        __syncthreads();
#pragma unroll
        for (int h = 0; h < 2; ++h) {
            v8s a_frag[4], b_frag[4];
#pragma unroll
            for (int mi = 0; mi < 4; ++mi)
                a_frag[mi] = *(const v8s*)&As[h * 4096 + (wm + mi * 16 + l15) * 32 + q * 8];
#pragma unroll
            for (int ni = 0; ni < 4; ++ni)
                b_frag[ni] = *(const v8s*)&Bs[h * 4096 + (wn + ni * 16 + l15) * 32 + q * 8];
#pragma unroll
            for (int mi = 0; mi < 4; ++mi)
#pragma unroll
                for (int ni = 0; ni < 4; ++ni)
                    acc[mi][ni] = __builtin_amdgcn_mfma_f32_16x16x32_bf16(
                        a_frag[mi], b_frag[ni], acc[mi][ni], 0, 0, 0);
        }
        __syncthreads();
    }

    // direct-store epilogue: bias preload per ni-column, then strided 2B stores
    float bcol[4];
#pragma unroll
    for (int ni = 0; ni < 4; ++ni)
        bcol[ni] = ldin(bias, boff + bn + wn + ni * 16 + l15, isf32);
#pragma unroll
    for (int mi = 0; mi < 4; ++mi) {
        int growb = bm + wm + mi * 16 + q * 4;
#pragma unroll
        for (int r = 0; r < 4; ++r) {
            int gm = growb + r;
            if (gm < M) {
                bf16* rowp = C + (size_t)gm * N + bn + wn + l15;
#pragma unroll
                for (int ni = 0; ni < 4; ++ni) {
                    float v = acc[mi][ni][r] + bcol[ni];
                    if (relu) v = fmaxf(v, 0.f);
                    rowp[ni * 16] = f2b(v);
                }
            }
        }
    }
}

// ---------------- MFMA GEMM 64x64, BK=64 (8 blocks/CU capacity; for K=256 GEMMs) ----------------
__global__ void __launch_bounds__(256) mfma_gemm64(const bf16* __restrict__ A,
                                                   const bf16* __restrict__ Wt,
                                                   const void* __restrict__ bias, size_t boff,
                                                   bf16* __restrict__ C,
                                                   int M, int N, int K, int relu,
                                                   const int* __restrict__ flag) {
    int isf32 = *flag;
    __shared__ __align__(16) char smem[16384];   // As+Bs (16384) / Cs (9216) overlay
    bf16* As = (bf16*)smem;               // [2][64][32]
    bf16* Bs = (bf16*)smem + 4096;        // [2][64][32]
    bf16* Cs = (bf16*)smem;               // 64 x 72 (16B-aligned rows)
    int tid = threadIdx.x;
    int lane = tid & 63, wave = tid >> 6;
    int wm = (wave & 1) * 32, wn = (wave >> 1) * 32;
    int bx, by;
    xcd_remap(bx, by);
    int bm = by * 64, bn = bx * 64;
    int q = lane >> 4, l15 = lane & 15;

    v4f acc[2][2];
#pragma unroll
    for (int i = 0; i < 2; ++i)
#pragma unroll
        for (int j = 0; j < 2; ++j) acc[i][j] = (v4f){0.f, 0.f, 0.f, 0.f};

    int srow = tid >> 2;
    int oct = (tid & 3) * 8;
    int am = bm + srow; if (am >= M) am = M - 1;
    const bf16* arow = A + (size_t)am * K + oct;
    const bf16* brow = Wt + (size_t)(bn + srow) * K + oct;
    bf16* lA0 = As + tid * 8;
    bf16* lA1 = As + 2048 + tid * 8;
    bf16* lB0 = Bs + tid * 8;
    bf16* lB1 = Bs + 2048 + tid * 8;

    for (int k0 = 0; k0 < K; k0 += 64) {
        GLDS16(arow + k0, lA0);
        GLDS16(arow + k0 + 32, lA1);
        GLDS16(brow + k0, lB0);
        GLDS16(brow + k0 + 32, lB1);
        __syncthreads();
#pragma unroll
        for (int h = 0; h < 2; ++h) {
            v8s a_frag[2], b_frag[2];
#pragma unroll
            for (int mi = 0; mi < 2; ++mi)
                a_frag[mi] = *(const v8s*)&As[h * 2048 + (wm + mi * 16 + l15) * 32 + q * 8];
#pragma unroll
            for (int ni = 0; ni < 2; ++ni)
                b_frag[ni] = *(const v8s*)&Bs[h * 2048 + (wn + ni * 16 + l15) * 32 + q * 8];
#pragma unroll
            for (int mi = 0; mi < 2; ++mi)
#pragma unroll
                for (int ni = 0; ni < 2; ++ni)
                    acc[mi][ni] = __builtin_amdgcn_mfma_f32_16x16x32_bf16(
                        a_frag[mi], b_frag[ni], acc[mi][ni], 0, 0, 0);
        }
        __syncthreads();
    }

#pragma unroll
    for (int ni = 0; ni < 2; ++ni) {
        int cn = wn + ni * 16 + l15;
        float bv = ldin(bias, boff + bn + cn, isf32);
#pragma unroll
        for (int mi = 0; mi < 2; ++mi) {
#pragma unroll
            for (int r = 0; r < 4; ++r) {
                float v = acc[mi][ni][r] + bv;
                if (relu) v = fmaxf(v, 0.f);
                Cs[(wm + mi * 16 + q * 4 + r) * 72 + cn] = f2b(v);
            }
        }
    }
    __syncthreads();
    {
        int row = tid >> 2, seg = tid & 3;
        int gm = bm + row;
        if (gm < M) {
            const bf16* srcp = Cs + row * 72 + seg * 16;
            bf16* dstp = C + (size_t)gm * N + bn + seg * 16;
            *(uint4*)(dstp) = *(const uint4*)(srcp);
            *(uint4*)(dstp + 8) = *(const uint4*)(srcp + 8);
        }
    }
}

// ---------------- MFMA GEMM 64x64, BK=128 (for FFN2: K=2048, grid 3.7/CU < 5-block cap) ----------------
__global__ void __launch_bounds__(256) mfma_gemm64k(const bf16* __restrict__ A,
                                                    const bf16* __restrict__ Wt,
                                                    const void* __restrict__ bias, size_t boff,
                                                    bf16* __restrict__ C,
                                                    int M, int N, int K, int relu,
                                                    const int* __restrict__ flag) {
    int isf32 = *flag;
    __shared__ __align__(16) char smem[32768];   // As [4][64][32] + Bs [4][64][32]; Cs overlay
    bf16* As = (bf16*)smem;
    bf16* Bs = (bf16*)smem + 8192;
    bf16* Cs = (bf16*)smem;               // 64 x 72
    int tid = threadIdx.x;
    int lane = tid & 63, wave = tid >> 6;
    int wm = (wave & 1) * 32, wn = (wave >> 1) * 32;
    int bx, by;
    xcd_remap(bx, by);
    int bm = by * 64, bn = bx * 64;
    int q = lane >> 4, l15 = lane & 15;

    v4f acc[2][2];
#pragma unroll
    for (int i = 0; i < 2; ++i)
#pragma unroll
        for (int j = 0; j < 2; ++j) acc[i][j] = (v4f){0.f, 0.f, 0.f, 0.f};

    int srow = tid >> 2;
    int oct = (tid & 3) * 8;
    int am = bm + srow; if (am >= M) am = M - 1;
    const bf16* arow = A + (size_t)am * K + oct;
    const bf16* brow = Wt + (size_t)(bn + srow) * K + oct;

    for (int k0 = 0; k0 < K; k0 += 128) {
#pragma unroll
        for (int h = 0; h < 4; ++h) {
            GLDS16(arow + k0 + h * 32, As + h * 2048 + tid * 8);
            GLDS16(brow + k0 + h * 32, Bs + h * 2048 + tid * 8);
        }
        __syncthreads();
#pragma unroll
        for (int h = 0; h < 4; ++h) {
            v8s a_frag[2], b_frag[2];
#pragma unroll
            for (int mi = 0; mi < 2; ++mi)
                a_frag[mi] = *(const v8s*)&As[h * 2048 + (wm + mi * 16 + l15) * 32 + q * 8];
#pragma unroll
            for (int ni = 0; ni < 2; ++ni)
                b_frag[ni] = *(const v8s*)&Bs[h * 2048 + (wn + ni * 16 + l15) * 32 + q * 8];
#pragma unroll
            for (int mi = 0; mi < 2; ++mi)
#pragma unroll
                for (int ni = 0; ni < 2; ++ni)
                    acc[mi][ni] = __builtin_amdgcn_mfma_f32_16x16x32_bf16(
                        a_frag[mi], b_frag[ni], acc[mi][ni], 0, 0, 0);
        }
        __syncthreads();
    }

#pragma unroll
    for (int ni = 0; ni < 2; ++ni) {
        int cn = wn + ni * 16 + l15;
        float bv = ldin(bias, boff + bn + cn, isf32);
#pragma unroll
        for (int mi = 0; mi < 2; ++mi) {
#pragma unroll
            for (int r = 0; r < 4; ++r) {
                float v = acc[mi][ni][r] + bv;
                if (relu) v = fmaxf(v, 0.f);
                Cs[(wm + mi * 16 + q * 4 + r) * 72 + cn] = f2b(v);
            }
        }
    }
    __syncthreads();
    {
        int row = tid >> 2, seg = tid & 3;
        int gm = bm + row;
        if (gm < M) {
            const bf16* srcp = Cs + row * 72 + seg * 16;
            bf16* dstp = C + (size_t)gm * N + bn + seg * 16;
            *(uint4*)(dstp) = *(const uint4*)(srcp);
            *(uint4*)(dstp + 8) = *(const uint4*)(srcp + 8);
        }
    }
}

// ---------------- fused value + q GEMM, one launch: grid (10, GM64), BK=64, K=256 ----------------
// bx<4 : value = xb @ Wvt (N=256 cols bx*64)
// bx>=4: [off|attn] = qb @ Wqt (N=384 cols (bx-4)*64); split epilogue off/attn.
__global__ void __launch_bounds__(256) mfma_gemm64_vq(const bf16* __restrict__ xb,
                                                      const bf16* __restrict__ qb,
                                                      const bf16* __restrict__ Wvt,
                                                      const bf16* __restrict__ Wqt,
                                                      const void* __restrict__ bv, size_t obv,
                                                      const void* __restrict__ bo, size_t obo,
                                                      const void* __restrict__ ba, size_t oba,
                                                      bf16* __restrict__ valueo,
                                                      bf16* __restrict__ offo,
                                                      bf16* __restrict__ attno,
                                                      int M, const int* __restrict__ flag) {
    const int K = 256;
    int isf32 = *flag;
    __shared__ __align__(16) char smem[16384];
    bf16* As = (bf16*)smem;               // [2][64][32]
    bf16* Bs = (bf16*)smem + 4096;        // [2][64][32]
    bf16* Cs = (bf16*)smem;               // 64 x 72
    int tid = threadIdx.x;
    int lane = tid & 63, wave = tid >> 6;
    int wm = (wave & 1) * 32, wn = (wave >> 1) * 32;
    int bx, by;
    xcd_remap(bx, by);
    int bm = by * 64;
    int isV = (bx < 4);
    int bn = isV ? bx * 64 : (bx - 4) * 64;     // value: 0..192; q: 0..320
    const bf16* A = isV ? xb : qb;
    const bf16* Wt = isV ? Wvt : Wqt;
    int q = lane >> 4, l15 = lane & 15;

    v4f acc[2][2];
#pragma unroll
    for (int i = 0; i < 2; ++i)
#pragma unroll
        for (int j = 0; j < 2; ++j) acc[i][j] = (v4f){0.f, 0.f, 0.f, 0.f};

    int srow = tid >> 2;
    int oct = (tid & 3) * 8;
    int am = bm + srow; if (am >= M) am = M - 1;
    const bf16* arow = A + (size_t)am * K + oct;
    const bf16* brow = Wt + (size_t)(bn + srow) * K + oct;
    bf16* lA0 = As + tid * 8;
    bf16* lA1 = As + 2048 + tid * 8;
    bf16* lB0 = Bs + tid * 8;
    bf16* lB1 = Bs + 2048 + tid * 8;

    for (int k0 = 0; k0 < K; k0 += 64) {
        GLDS16(arow + k0, lA0);
        GLDS16(arow + k0 + 32, lA1);
        GLDS16(brow + k0, lB0);
        GLDS16(brow + k0 + 32, lB1);
        __syncthreads();
#pragma unroll
        for (int h = 0; h < 2; ++h) {
            v8s a_frag[2], b_frag[2];
#pragma unroll
            for (int mi = 0; mi < 2; ++mi)
                a_frag[mi] = *(const v8s*)&As[h * 2048 + (wm + mi * 16 + l15) * 32 + q * 8];
#pragma unroll
            for (int ni = 0; ni < 2; ++ni)
                b_frag[ni] = *(const v8s*)&Bs[h * 2048 + (wn + ni * 16 + l15) * 32 + q * 8];
#pragma unroll
            for (int mi = 0; mi < 2; ++mi)
#pragma unroll
                for (int ni = 0; ni < 2; ++ni)
                    acc[mi][ni] = __builtin_amdgcn_mfma_f32_16x16x32_bf16(
                        a_frag[mi], b_frag[ni], acc[mi][ni], 0, 0, 0);
        }
        __syncthreads();
    }

    // block-uniform output routing
    bf16* outp; int outN, colbase; const void* bptr; size_t bofs;
    if (isV)             { outp = valueo; outN = 256; colbase = bn;       bptr = bv; bofs = obv; }
    else if (bn < 256)   { outp = offo;   outN = 256; colbase = bn;       bptr = bo; bofs = obo; }
    else                 { outp = attno;  outN = 128; colbase = bn - 256; bptr = ba; bofs = oba; }

#pragma unroll
    for (int ni = 0; ni < 2; ++ni) {
        int cn = wn + ni * 16 + l15;
        float bvf = ldin(bptr, bofs + colbase + cn, isf32);
#pragma unroll
        for (int mi = 0; mi < 2; ++mi) {
#pragma unroll
            for (int r = 0; r < 4; ++r) {
                Cs[(wm + mi * 16 + q * 4 + r) * 72 + cn] = f2b(acc[mi][ni][r] + bvf);
            }
        }
    }
    __syncthreads();
    {
        int row = tid >> 2, seg = tid & 3;
        int gm = bm + row;
        if (gm < M) {
            const bf16* srcp = Cs + row * 72 + seg * 16;
            bf16* dstp = outp + (size_t)gm * outN + colbase + seg * 16;
            *(uint4*)(dstp) = *(const uint4*)(srcp);
            *(uint4*)(dstp + 8) = *(const uint4*)(srcp + 8);
        }
    }
}

// ---------------- fallback VALU GEMM ----------------
template<typename TA, int ADDPOS, int RELU>
__global__ void __launch_bounds__(256) gemm_bias(const TA* __restrict__ A,
                                                 const bf16* __restrict__ Apos,
                                                 const void* __restrict__ W, size_t woff,
                                                 const void* __restrict__ bias, size_t boff,
                                                 bf16* __restrict__ C,
                                                 int M, int N, int K,
                                                 const int* __restrict__ flag) {
    int isf32 = *flag;
    __shared__ float As[16][65];
    __shared__ float Bs[16][65];
    int tid = threadIdx.x;
    int tx = tid & 15;
    int ty = tid >> 4;
    int bm = blockIdx.y * 64;
    int bn = blockIdx.x * 64;
    float acc[4][4] = {};
    for (int k0 = 0; k0 < K; k0 += 16) {
#pragma unroll
        for (int e = 0; e < 4; ++e) {
            int idx = tid + e * 256;
            int mm = idx >> 4;
            int kk = idx & 15;
            int gm = bm + mm;
            float av = 0.f;
            if (gm < M) {
                size_t ai = (size_t)gm * K + k0 + kk;
                if (sizeof(TA) == 4) av = ((const float*)A)[ai];
                else                 av = b2f(((const bf16*)A)[ai]);
                if (ADDPOS) av += b2f(Apos[ai]);
            }
            As[kk][mm] = av;
        }
#pragma unroll
        for (int e = 0; e < 4; ++e) {
            int idx = tid + e * 256;
            int kk = idx >> 6;
            int nn = idx & 63;
            int gn = bn + nn;
            Bs[kk][nn] = (gn < N) ? ldin(W, woff + (size_t)(k0 + kk) * N + gn, isf32) : 0.f;
        }
        __syncthreads();
#pragma unroll
        for (int kk = 0; kk < 16; ++kk) {
            float a[4], b[4];
#pragma unroll
            for (int i = 0; i < 4; ++i) a[i] = As[kk][ty + 16 * i];
#pragma unroll
            for (int j = 0; j < 4; ++j) b[j] = Bs[kk][tx + 16 * j];
#pragma unroll
            for (int i = 0; i < 4; ++i)
#pragma unroll
                for (int j = 0; j < 4; ++j) acc[i][j] += a[i] * b[j];
        }
        __syncthreads();
    }
#pragma unroll
    for (int i = 0; i < 4; ++i) {
        int gm = bm + ty + 16 * i;
        if (gm >= M) continue;
#pragma unroll
        for (int j = 0; j < 4; ++j) {
            int gn = bn + tx + 16 * j;
            if (gn >= N) continue;
            float v = acc[i][j] + ldin(bias, boff + gn, isf32);
            if (RELU) v = fmaxf(v, 0.f);
            C[(size_t)gm * N + gn] = f2b(v);
        }
    }
}

// ---------------- MS-deform sampling: 4 rows/block, wave-parallel softmax ----------------
__global__ void __launch_bounds__(256) msdeform_sample4(const bf16* __restrict__ value,
                                                        const bf16* __restrict__ off,
                                                        const bf16* __restrict__ logits,
                                                        const float* __restrict__ refpts,
                                                        bf16* __restrict__ out) {
    __shared__ float sAttn[4 * 128];
    __shared__ int2 sIW[4 * 520];
    const int LH[4] = {76, 38, 19, 1};
    const int LW[4] = {76, 38, 19, 20};
    const int LS[4] = {0, 5776, 7220, 7581};
    int tid = threadIdx.x;
    int m0 = blockIdx.x * 4;

    for (int i = tid; i < 4 * 128; i += 256) {
        int r = i >> 7, li = i & 127;
        int m = m0 + r;
        int mc = (m < BM) ? m : BM - 1;
        sAttn[i] = b2f(logits[(size_t)mc * 128 + li]);
    }
    __syncthreads();
    {
        // 32 groups (4 rows x 8 heads) x 16 logits; 8 threads/group, 2 elems/thread.
        int g = tid >> 3, j = tid & 7;
        float* gp = sAttn + g * 16;
        float e0 = gp[j * 2], e1 = gp[j * 2 + 1];
        float mx = fmaxf(e0, e1);
#pragma unroll
        for (int o = 1; o < 8; o <<= 1) mx = fmaxf(mx, __shfl_xor(mx, o));
        e0 = __expf(e0 - mx);
        e1 = __expf(e1 - mx);
        float sm = e0 + e1;
#pragma unroll
        for (int o = 1; o < 8; o <<= 1) sm += __shfl_xor(sm, o);
        float inv = 1.f / sm;
        gp[j * 2] = e0 * inv;
        gp[j * 2 + 1] = e1 * inv;
    }
    __syncthreads();
    for (int i = tid; i < 4 * 128; i += 256) {
        int r = i >> 7, oi = i & 127;
        int m = m0 + r;
        int mc = (m < BM) ? m : BM - 1;
        int b = mc / S_TOT;
        int s = mc - b * S_TOT;
        int h = oi >> 4;
        int l = (oi >> 2) & 3;
        int H = LH[l], W = LW[l], st = LS[l];
        float fW = (float)W, fH = (float)H;
        float refx = refpts[s * 2 + 0];
        float refy = refpts[s * 2 + 1];
        ushort2 ov = *(const ushort2*)(off + (size_t)mc * 256 + oi * 2);
        float a = sAttn[r * 128 + oi];
        float xpix = (refx + b2f(ov.x) / fW) * fW - 0.5f;
        float ypix = (refy + b2f(ov.y) / fH) * fH - 0.5f;
        float x0f = floorf(xpix), y0f = floorf(ypix);
        int x0 = (int)x0f, y0 = (int)y0f;
        float wx1 = xpix - x0f, wy1 = ypix - y0f;
        float wx0 = 1.f - wx1, wy0 = 1.f - wy1;
        int vb = b * (S_TOT * 256) + h * 32;
        int base = r * 520 + h * 65 + (oi & 15) * 4;
#pragma unroll
        for (int c = 0; c < 4; ++c) {
            int cx = c & 1, cy = c >> 1;
            int xi = x0 + cx, yi = y0 + cy;
            float w = (cx ? wx1 : wx0) * (cy ? wy1 : wy0) * a;
            bool valid = (xi >= 0) && (xi <= W - 1) && (yi >= 0) && (yi <= H - 1);
            int xic = min(max(xi, 0), W - 1), yic = min(max(yi, 0), H - 1);
            int2 d;
            d.x = vb + (st + yic * W + xic) * 256;
            d.y = __float_as_int(valid ? w : 0.f);
            sIW[base + c] = d;
        }
    }
    __syncthreads();
    int r = tid >> 6, u = tid & 63;
    int h = u >> 3, d4 = (u & 7) * 4;
    int m = m0 + r;
    int cb = r * 520 + h * 65;
    float acc0 = 0.f, acc1 = 0.f, acc2 = 0.f, acc3 = 0.f;
#pragma unroll 8
    for (int c = 0; c < 64; ++c) {
        int2 p = sIW[cb + c];
        float w = __int_as_float(p.y);
        ushort4 v = *(const ushort4*)(value + p.x + d4);
        acc0 += w * b2f(v.x);
        acc1 += w * b2f(v.y);
        acc2 += w * b2f(v.z);
        acc3 += w * b2f(v.w);
    }
    if (m < BM) {
        ushort4 o;
        o.x = f2b(acc0); o.y = f2b(acc1); o.z = f2b(acc2); o.w = f2b(acc3);
        *(ushort4*)(out + (size_t)m * 256 + h * 32 + d4) = o;
    }
}

// ---------------- residual + LayerNorm: 4 rows/block, 1 wave/row; optional xb and qb=bf16(x+pos) ----------------
__global__ void __launch_bounds__(256) residual_ln4(float* __restrict__ x,
                                                    const bf16* __restrict__ y,
                                                    const void* __restrict__ g, size_t goff,
                                                    const void* __restrict__ beta, size_t boff,
                                                    const int* __restrict__ flag,
                                                    bf16* __restrict__ xb,
                                                    const bf16* __restrict__ pos,
                                                    bf16* __restrict__ qb) {
    int isf32 = *flag;
    int tid = threadIdx.x;
    int r = tid >> 6, lane = tid & 63;
    int m = blockIdx.x * 4 + r;
    if (m >= BM) return;
    size_t o = (size_t)m * 256 + lane * 4;
    float4 xv = *(const float4*)(x + o);
    ushort4 yv = *(const ushort4*)(y + o);
    float r0 = xv.x + b2f(yv.x), r1 = xv.y + b2f(yv.y);
    float r2 = xv.z + b2f(yv.z), r3 = xv.w + b2f(yv.w);
    float sum = r0 + r1 + r2 + r3;
#pragma unroll
    for (int ofs = 32; ofs > 0; ofs >>= 1) sum += __shfl_xor(sum, ofs);
    float mean = sum * (1.f / 256.f);
    float d0 = r0 - mean, d1 = r1 - mean, d2 = r2 - mean, d3 = r3 - mean;
    float vv = d0 * d0 + d1 * d1 + d2 * d2 + d3 * d3;
#pragma unroll
    for (int ofs = 32; ofs > 0; ofs >>= 1) vv += __shfl_xor(vv, ofs);
    float rstd = rsqrtf(vv * (1.f / 256.f) + 1e-5f);
    int c = lane * 4;
    float o0 = d0 * rstd * ldin(g, goff + c + 0, isf32) + ldin(beta, boff + c + 0, isf32);
    float o1 = d1 * rstd * ldin(g, goff + c + 1, isf32) + ldin(beta, boff + c + 1, isf32);
    float o2 = d2 * rstd * ldin(g, goff + c + 2, isf32) + ldin(beta, boff + c + 2, isf32);
    float o3 = d3 * rstd * ldin(g, goff + c + 3, isf32) + ldin(beta, boff + c + 3, isf32);
    *(float4*)(x + o) = make_float4(o0, o1, o2, o3);
    if (xb) {
        ushort4 xo;
        xo.x = f2b(o0); xo.y = f2b(o1); xo.z = f2b(o2); xo.w = f2b(o3);
        *(ushort4*)(xb + o) = xo;
    }
    if (qb) {
        ushort4 pv = *(const ushort4*)(pos + o);
        ushort4 qo;
        qo.x = f2b(o0 + b2f(pv.x));
        qo.y = f2b(o1 + b2f(pv.y));
        qo.z = f2b(o2 + b2f(pv.z));
        qo.w = f2b(o3 + b2f(pv.w));
        *(ushort4*)(qb + o) = qo;
    }
}

// ---------------- host ----------------
extern "C" void kernel_launch(void* const* d_in, const int* in_sizes, int n_in,
                              void* d_out, int out_size, void* d_ws, size_t ws_size,
                              hipStream_t stream) {
    (void)in_sizes; (void)n_in; (void)out_size;
    const size_t MS = (size_t)BM * DMODEL;   // 3,891,712

    char* base = (char*)d_ws;
    int* flag    = (int*)base;    base += 256;
    float* x     = (float*)base;  base += MS * 4;
    bf16* value  = (bf16*)base;   base += MS * 2;
    bf16* attnl  = (bf16*)base;   base += (size_t)BM * 128 * 2;
    bf16* pos    = (bf16*)base;   base += MS * 2;
    bf16* offms  = (bf16*)base;   base += MS * 2;   // off -> msout in place
    bf16* yb     = (bf16*)base;   base += MS * 2;   // also qb (dead before Wo writes)
    size_t base_used = (size_t)(base - (char*)d_ws);

    // transposed-weight element counts per layer
    const size_t SZ_WVT = 65536, SZ_WQT = 98304, SZ_WOT = 65536, SZ_W1T = 524288, SZ_W2T = 524288;
    const size_t WB1 = (SZ_WVT + SZ_WQT + SZ_WOT + SZ_W1T + SZ_W2T) * 2;   // bytes per layer

    bf16* xb = (bf16*)base;
    size_t needB  = base_used + MS * 2 + WB1 + (size_t)S_TOT * 8 + 1024;
    size_t needAH = ((base_used + MS * 2 + 6 * WB1 + (size_t)S_TOT * 8 + 1024 + 255) & ~(size_t)255)
                  + (size_t)BM * 2048 * 2;
    bool FAST = ws_size >= needB;
    bool W6   = ws_size >= needAH;      // 6-layer weights + full hidden
    int  nL   = W6 ? 6 : 1;

    bf16 *W1t = nullptr, *W2t = nullptr, *Wvt = nullptr, *Wqt = nullptr, *Wot = nullptr;
    float* ref;
    bf16* hiddenF = nullptr;
    bool FULLH = false;
    if (FAST) {
        char* p = (char*)xb + MS * 2;
        Wvt = (bf16*)p;  p += (size_t)nL * SZ_WVT * 2;
        Wqt = (bf16*)p;  p += (size_t)nL * SZ_WQT * 2;
        Wot = (bf16*)p;  p += (size_t)nL * SZ_WOT * 2;
        W1t = (bf16*)p;  p += (size_t)nL * SZ_W1T * 2;
        W2t = (bf16*)p;  p += (size_t)nL * SZ_W2T * 2;
        ref = (float*)p; p += (size_t)S_TOT * 2 * 4;
        size_t used = (size_t)(p - (char*)d_ws);
        used = (used + 255) & ~(size_t)255;
        if (ws_size >= used + (size_t)BM * 2048 * 2) {
            hiddenF = (bf16*)((char*)d_ws + used);
            FULLH = true;
        }
    } else {
        ref = (float*)base;
    }

    bf16* hidden = FULLH ? hiddenF : value;
    const int CH = FULLH ? BM : 2816;

    detect_dtype<<<1, 256, 0, stream>>>((const unsigned short*)d_in[0], flag);

    {
        int HW0 = 76 * 76, HW1 = 38 * 38, HW2 = 19 * 19;
        int n0 = BATCH * HW0 * 256, n1 = BATCH * HW1 * 256, n2 = BATCH * HW2 * 256;
        pack_level<<<(n0 + 255) / 256, 256, 0, stream>>>(d_in[0], d_in[1], d_in[8], 0, x, pos, HW0, 0, flag);
        pack_level<<<(n1 + 255) / 256, 256, 0, stream>>>(d_in[2], d_in[3], d_in[8], 1, x, pos, HW1, 5776, flag);
        pack_level<<<(n2 + 255) / 256, 256, 0, stream>>>(d_in[4], d_in[5], d_in[8], 2, x, pos, HW2, 7220, flag);
        int nt = BATCH * 20 * 256;
        pack_task<<<(nt + 255) / 256, 256, 0, stream>>>(d_in[6], d_in[7], x, pos, flag);
        make_ref<<<(S_TOT + 255) / 256, 256, 0, stream>>>(ref);
    }

    const int GM64 = (BM + 63) / 64;      // 238
    const int GR4 = (BM + 3) / 4;         // 3801
    const int n4 = (int)(MS / 4);

    if (FAST) {
        cvt_xq<<<(n4 + 255) / 256, 256, 0, stream>>>(x, pos, xb, yb, n4);   // xb + qb (layer 0)
        if (W6) {   // all 6 layers' weight transposes upfront, one launch
            transpose_all<<<dim3(1248, 6), 256, 0, stream>>>(d_in[13], d_in[9], d_in[11], d_in[15],
                                                             d_in[17], d_in[19],
                                                             Wvt, Wqt, Wot, W1t, W2t, -1, flag);
        }
    }

    for (int L = 0; L < 6; ++L) {
        size_t oW256 = (size_t)L * 256 * 256, ob256 = (size_t)L * 256;
        size_t oW128 = (size_t)L * 256 * 128, ob128 = (size_t)L * 128;
        size_t oW1   = (size_t)L * 256 * 2048, ob1  = (size_t)L * 2048;
        size_t oW2   = (size_t)L * 2048 * 256;

        if (FAST) {
            bf16* WvtL = Wvt + (W6 ? (size_t)L * SZ_WVT : 0);
            bf16* WqtL = Wqt + (W6 ? (size_t)L * SZ_WQT : 0);
            bf16* WotL = Wot + (W6 ? (size_t)L * SZ_WOT : 0);
            bf16* W1tL = W1t + (W6 ? (size_t)L * SZ_W1T : 0);
            bf16* W2tL = W2t + (W6 ? (size_t)L * SZ_W2T : 0);
            if (!W6) {
                transpose_all<<<dim3(1248, 1), 256, 0, stream>>>(d_in[13], d_in[9], d_in[11], d_in[15],
                                                                 d_in[17], d_in[19],
                                                                 Wvt, Wqt, Wot, W1t, W2t, L, flag);
            }
            bf16* qb = yb;
            mfma_gemm64_vq<<<dim3(10, GM64), 256, 0, stream>>>(xb, qb, WvtL, WqtL,
                                                               d_in[14], ob256, d_in[10], ob256,
                                                               d_in[12], ob128,
                                                               value, offms, attnl, BM, flag);

            msdeform_sample4<<<GR4, 256, 0, stream>>>(value, offms, attnl, ref, offms);

            mfma_gemm64<<<dim3(4, GM64), 256, 0, stream>>>(offms, WotL, d_in[16], ob256, yb, BM, 256, 256, 0, flag);
            residual_ln4<<<GR4, 256, 0, stream>>>(x, yb, d_in[21], ob256, d_in[22], ob256, flag, xb, nullptr, nullptr);

            for (int r0 = 0; r0 < BM; r0 += CH) {
                int mc = BM - r0 < CH ? BM - r0 : CH;
                int gmc128 = (mc + 127) / 128;
                int gmc64 = (mc + 63) / 64;
                mfma_gemm<<<dim3(16, gmc128), 256, 0, stream>>>(xb + (size_t)r0 * 256, W1tL, d_in[18], ob1,
                                                                hidden, mc, 2048, 256, 1, flag);
                mfma_gemm64k<<<dim3(4, gmc64), 256, 0, stream>>>(hidden, W2tL, d_in[20], ob256,
                                                                 yb + (size_t)r0 * 256, mc, 256, 2048, 0, flag);
            }
            residual_ln4<<<GR4, 256, 0, stream>>>(x, yb, d_in[23], ob256, d_in[24], ob256, flag, xb,
                                                  (L < 5) ? pos : nullptr, (L < 5) ? yb : nullptr);
        } else {
            dim3 g256(4, GM64);
            dim3 g128(2, GM64);
            gemm_bias<float, 0, 0><<<g256, 256, 0, stream>>>(x, nullptr, d_in[13], oW256, d_in[14], ob256,
                                                             value, BM, 256, 256, flag);
            gemm_bias<float, 1, 0><<<g256, 256, 0, stream>>>(x, pos, d_in[9], oW256, d_in[10], ob256,
                                                             offms, BM, 256, 256, flag);
            gemm_bias<float, 1, 0><<<g128, 256, 0, stream>>>(x, pos, d_in[11], oW128, d_in[12], ob128,
                                                             attnl, BM, 128, 256, flag);
            msdeform_sample4<<<GR4, 256, 0, stream>>>(value, offms, attnl, ref, offms);
            gemm_bias<bf16, 0, 0><<<g256, 256, 0, stream>>>(offms, nullptr, d_in[15], oW256, d_in[16], ob256,
                                                            yb, BM, 256, 256, flag);
            residual_ln4<<<GR4, 256, 0, stream>>>(x, yb, d_in[21], ob256, d_in[22], ob256, flag, nullptr, nullptr, nullptr);
            for (int r0 = 0; r0 < BM; r0 += CH) {
                int mc = BM - r0 < CH ? BM - r0 : CH;
                dim3 gh(32, (mc + 63) / 64);
                dim3 go(4, (mc + 63) / 64);
                gemm_bias<float, 0, 1><<<gh, 256, 0, stream>>>(x + (size_t)r0 * 256, nullptr, d_in[17], oW1,
                                                               d_in[18], ob1, hidden, mc, 2048, 256, flag);
                gemm_bias<bf16, 0, 0><<<go, 256, 0, stream>>>(hidden, nullptr, d_in[19], oW2, d_in[20], ob256,
                                                              yb + (size_t)r0 * 256, mc, 256, 2048, flag);
            }
            residual_ln4<<<GR4, 256, 0, stream>>>(x, yb, d_in[23], ob256, d_in[24], ob256, flag, nullptr, nullptr, nullptr);
        }
    }

    cast_out<<<((int)MS + 255) / 256, 256, 0, stream>>>(x, d_out, (int)MS, flag);
}

// Round 8
// 1097.092 us; speedup vs baseline: 1.0962x; 1.0348x over previous
//
#include <hip/hip_runtime.h>

#define S_TOT 7601
#define BATCH 2
#define BM (BATCH * S_TOT)   // 15202
#define DMODEL 256

typedef unsigned short bf16;
typedef __attribute__((ext_vector_type(8))) short v8s;
typedef __attribute__((ext_vector_type(4))) float v4f;
typedef __attribute__((ext_vector_type(8))) unsigned short u16x8;

__device__ __forceinline__ float b2f(bf16 u) {
    union { unsigned int i; float f; } v;
    v.i = ((unsigned int)u) << 16;
    return v.f;
}
__device__ __forceinline__ bf16 f2b(float f) {
    union { unsigned int i; float f; } v;
    v.f = f;
    unsigned int r = v.i + 0x7FFFu + ((v.i >> 16) & 1u);
    return (bf16)(r >> 16);
}
__device__ __forceinline__ float ldin(const void* p, size_t i, int isf32) {
    return isf32 ? ((const float*)p)[i] : b2f(((const bf16*)p)[i]);
}

// async global->LDS, 16B per lane. LDS dest must be linear: wave-uniform base + lane*16.
#define GLDS16(gp, lp)                                                          \
    __builtin_amdgcn_global_load_lds(                                           \
        (const __attribute__((address_space(1))) unsigned int*)(gp),            \
        (__attribute__((address_space(3))) unsigned int*)(lp), 16, 0, 0)

// bijective XCD-chunked block remap (m204): consecutive logical blocks land on one XCD.
__device__ __forceinline__ void xcd_remap(int& bx, int& by) {
    int gx = gridDim.x, gy = gridDim.y;
    int nwg = gx * gy;
    int lin = blockIdx.y * gx + blockIdx.x;
    int q = nwg >> 3, r = nwg & 7;
    int xcd = lin & 7, idx = lin >> 3;
    int lin2 = (xcd < r ? xcd * (q + 1) : r * (q + 1) + (xcd - r) * q) + idx;
    bx = lin2 % gx;
    by = lin2 / gx;
}

// ---------------- dtype probe ----------------
__global__ void detect_dtype(const unsigned short* __restrict__ src, int* __restrict__ flag) {
    __shared__ int cnt;
    if (threadIdx.x == 0) cnt = 0;
    __syncthreads();
    int local = 0;
    for (int i = threadIdx.x; i < 16384; i += 256) {
        unsigned int e = (src[i] >> 7) & 0xFFu;
        if (e >= 143u) local++;
    }
    atomicAdd(&cnt, local);
    __syncthreads();
    if (threadIdx.x == 0) *flag = (cnt > 200) ? 1 : 0;
}

// ---------------- pack ----------------
__global__ void __launch_bounds__(256) pack_level(const void* __restrict__ src,
                                                  const void* __restrict__ pin,
                                                  const void* __restrict__ lemb, int lrow,
                                                  float* __restrict__ x,
                                                  bf16* __restrict__ pout,
                                                  int HW, int start,
                                                  const int* __restrict__ flag) {
    int isf32 = *flag;
    int i = blockIdx.x * 256 + threadIdx.x;
    int total = BATCH * HW * 256;
    if (i >= total) return;
    int c = i & 255;
    int t = i >> 8;
    int s = t % HW;
    int b = t / HW;
    size_t src_idx = ((size_t)b * 256 + c) * HW + s;
    float sv = ldin(src, src_idx, isf32);
    float pv = ldin(pin, src_idx, isf32) + ldin(lemb, (size_t)lrow * 256 + c, isf32);
    size_t o = ((size_t)b * S_TOT + start + s) * 256 + c;
    x[o] = sv;
    pout[o] = f2b(pv);
}

__global__ void __launch_bounds__(256) pack_task(const void* __restrict__ te,
                                                 const void* __restrict__ tpe,
                                                 float* __restrict__ x,
                                                 bf16* __restrict__ pout,
                                                 const int* __restrict__ flag) {
    int isf32 = *flag;
    int i = blockIdx.x * 256 + threadIdx.x;
    int total = BATCH * 20 * 256;
    if (i >= total) return;
    int c = i & 255;
    int t = (i >> 8) % 20;
    int b = (i >> 8) / 20;
    size_t o = ((size_t)b * S_TOT + 7581 + t) * 256 + c;
    x[o] = ldin(te, ((size_t)b * 20 + t) * 256 + c, isf32);
    pout[o] = f2b(ldin(tpe, (size_t)t * 256 + c, isf32));
}

__global__ void __launch_bounds__(256) make_ref(float* __restrict__ ref) {
    int s = blockIdx.x * 256 + threadIdx.x;
    if (s >= S_TOT) return;
    int H, W, st;
    if (s < 5776)      { H = 76; W = 76; st = 0; }
    else if (s < 7220) { H = 38; W = 38; st = 5776; }
    else if (s < 7581) { H = 19; W = 19; st = 7220; }
    else               { H = 1;  W = 20; st = 7581; }
    int r = s - st;
    int i = r / W, j = r % W;
    ref[s * 2 + 0] = (j + 0.5f) / (float)W;
    ref[s * 2 + 1] = (i + 0.5f) / (float)H;
}

// ---------------- cvt: xb = bf16(x), qb = bf16(x + pos) — single pass over x ----------------
__global__ void __launch_bounds__(256) cvt_xq(const float* __restrict__ x,
                                              const bf16* __restrict__ pos,
                                              bf16* __restrict__ xb,
                                              bf16* __restrict__ qb, int n4) {
    int i = blockIdx.x * 256 + threadIdx.x;
    if (i >= n4) return;
    float4 xv = ((const float4*)x)[i];
    ushort4 pv = ((const ushort4*)pos)[i];
    ushort4 xo, qo;
    xo.x = f2b(xv.x); xo.y = f2b(xv.y); xo.z = f2b(xv.z); xo.w = f2b(xv.w);
    qo.x = f2b(xv.x + b2f(pv.x));
    qo.y = f2b(xv.y + b2f(pv.y));
    qo.z = f2b(xv.z + b2f(pv.z));
    qo.w = f2b(xv.w + b2f(pv.w));
    ((ushort4*)xb)[i] = xo;
    ((ushort4*)qb)[i] = qo;
}

// ---------------- all-weights transpose: 1248 tiles of 32x32 per layer ----------------
// L0 >= 0: single layer L0, dst at base. L0 < 0: layer = blockIdx.y, dst offset by stride.
// Woff -> Wqt rows 0..255, Wa -> Wqt rows 256..383 (fused q-GEMM weight).
__global__ void __launch_bounds__(256) transpose_all(const void* __restrict__ Wv,
                                                     const void* __restrict__ Woff,
                                                     const void* __restrict__ Wa,
                                                     const void* __restrict__ Wo,
                                                     const void* __restrict__ W1,
                                                     const void* __restrict__ W2,
                                                     bf16* __restrict__ Wvt,
                                                     bf16* __restrict__ Wqt,
                                                     bf16* __restrict__ Wot,
                                                     bf16* __restrict__ W1t,
                                                     bf16* __restrict__ W2t,
                                                     int L0, const int* __restrict__ flag) {
    int isf32 = *flag;
    int L = (L0 >= 0) ? L0 : (int)blockIdx.y;
    size_t dl = (L0 >= 0) ? 0 : (size_t)blockIdx.y;
    int t = blockIdx.x;
    const void* src; bf16* dst; int K, N; size_t woff; int rowoff = 0;
    if (t < 64)        { src = Wv;   dst = Wvt + dl * 65536;  K = 256;  N = 256;  woff = (size_t)L * 65536; }
    else if (t < 128)  { src = Woff; dst = Wqt + dl * 98304;  K = 256;  N = 256;  woff = (size_t)L * 65536;  t -= 64; }
    else if (t < 160)  { src = Wa;   dst = Wqt + dl * 98304;  K = 256;  N = 128;  woff = (size_t)L * 32768;  rowoff = 256; t -= 128; }
    else if (t < 224)  { src = Wo;   dst = Wot + dl * 65536;  K = 256;  N = 256;  woff = (size_t)L * 65536;  t -= 160; }
    else if (t < 736)  { src = W1;   dst = W1t + dl * 524288; K = 256;  N = 2048; woff = (size_t)L * 524288; t -= 224; }
    else               { src = W2;   dst = W2t + dl * 524288; K = 2048; N = 256;  woff = (size_t)L * 524288; t -= 736; }
    int ntx = N >> 5;
    int tk = (t / ntx) * 32;
    int tn = (t % ntx) * 32;
    __shared__ float tl[32][33];
    int r = threadIdx.x >> 3;
    int c4 = (threadIdx.x & 7) * 4;
#pragma unroll
    for (int i = 0; i < 4; ++i)
        tl[r][c4 + i] = ldin(src, woff + (size_t)(tk + r) * N + tn + c4 + i, isf32);
    __syncthreads();
#pragma unroll
    for (int i = 0; i < 4; ++i)
        dst[(size_t)(tn + r + rowoff) * K + tk + c4 + i] = f2b(tl[c4 + i][r]);
}

// ---------------- MFMA GEMM 128x128, BK=64, direct-store epilogue (proven r7) ----------------
__global__ void __launch_bounds__(256) mfma_gemm(const bf16* __restrict__ A,
                                                 const bf16* __restrict__ Wt,
                                                 const void* __restrict__ bias, size_t boff,
                                                 bf16* __restrict__ C,
                                                 int M, int N, int K, int relu,
                                                 const int* __restrict__ flag) {
    int isf32 = *flag;
    __shared__ __align__(16) char smem[32768];   // As+Bs only
    bf16* As = (bf16*)smem;               // [2][128][32]
    bf16* Bs = (bf16*)smem + 8192;        // [2][128][32]
    int tid = threadIdx.x;
    int lane = tid & 63, wave = tid >> 6;
    int wm = (wave & 1) << 6, wn = (wave >> 1) << 6;
    int bx, by;
    xcd_remap(bx, by);
    int bm = by * 128, bn = bx * 128;
    int q = lane >> 4, l15 = lane & 15;

    v4f acc[4][4];
#pragma unroll
    for (int i = 0; i < 4; ++i)
#pragma unroll
        for (int j = 0; j < 4; ++j) acc[i][j] = (v4f){0.f, 0.f, 0.f, 0.f};

    int r0 = tid >> 2, r1 = r0 + 64;
    int oct = (tid & 3) * 8;
    int am0 = bm + r0; if (am0 >= M) am0 = M - 1;
    int am1 = bm + r1; if (am1 >= M) am1 = M - 1;
    const bf16* ag0 = A + (size_t)am0 * K + oct;
    const bf16* ag1 = A + (size_t)am1 * K + oct;
    const bf16* bg0 = Wt + (size_t)(bn + r0) * K + oct;
    const bf16* bg1 = Wt + (size_t)(bn + r1) * K + oct;
    bf16* lA0 = As + tid * 8;
    bf16* lA1 = As + (tid + 256) * 8;
    bf16* lA2 = As + 4096 + tid * 8;
    bf16* lA3 = As + 4096 + (tid + 256) * 8;
    bf16* lB0 = Bs + tid * 8;
    bf16* lB1 = Bs + (tid + 256) * 8;
    bf16* lB2 = Bs + 4096 + tid * 8;
    bf16* lB3 = Bs + 4096 + (tid + 256) * 8;

    for (int k0 = 0; k0 < K; k0 += 64) {
        GLDS16(ag0 + k0, lA0);
        GLDS16(ag1 + k0, lA1);
        GLDS16(ag0 + k0 + 32, lA2);
        GLDS16(ag1 + k0 + 32, lA3);
        GLDS16(bg0 + k0, lB0);
        GLDS16(bg1 + k0, lB1);
        GLDS16(bg0 + k0 + 32, lB2);
        GLDS16(bg1 + k0 + 32, lB3);
        __syncthreads();
#pragma unroll
        for (int h = 0; h < 2; ++h) {
            v8s a_frag[4], b_frag[4];
#pragma unroll
            for (int mi = 0; mi < 4; ++mi)
                a_frag[mi] = *(const v8s*)&As[h * 4096 + (wm + mi * 16 + l15) * 32 + q * 8];
#pragma unroll
            for (int ni = 0; ni < 4; ++ni)
                b_frag[ni] = *(const v8s*)&Bs[h * 4096 + (wn + ni * 16 + l15) * 32 + q * 8];
#pragma unroll
            for (int mi = 0; mi < 4; ++mi)
#pragma unroll
                for (int ni = 0; ni < 4; ++ni)
                    acc[mi][ni] = __builtin_amdgcn_mfma_f32_16x16x32_bf16(
                        a_frag[mi], b_frag[ni], acc[mi][ni], 0, 0, 0);
        }
        __syncthreads();
    }

    float bcol[4];
#pragma unroll
    for (int ni = 0; ni < 4; ++ni)
        bcol[ni] = ldin(bias, boff + bn + wn + ni * 16 + l15, isf32);
#pragma unroll
    for (int mi = 0; mi < 4; ++mi) {
        int growb = bm + wm + mi * 16 + q * 4;
#pragma unroll
        for (int r = 0; r < 4; ++r) {
            int gm = growb + r;
            if (gm < M) {
                bf16* rowp = C + (size_t)gm * N + bn + wn + l15;
#pragma unroll
                for (int ni = 0; ni < 4; ++ni) {
                    float v = acc[mi][ni][r] + bcol[ni];
                    if (relu) v = fmaxf(v, 0.f);
                    rowp[ni * 16] = f2b(v);
                }
            }
        }
    }
}

// ---------------- fused value + q GEMM, 128x128 tiles, direct-store, K=256 ----------------
// grid (5, 119): bx 0,1 -> value = xb @ Wvt (cols bx*128); bx 2,3 -> off; bx 4 -> attn.
__global__ void __launch_bounds__(256) mfma_gemm_vq128(const bf16* __restrict__ xb,
                                                       const bf16* __restrict__ qb,
                                                       const bf16* __restrict__ Wvt,
                                                       const bf16* __restrict__ Wqt,
                                                       const void* __restrict__ bv, size_t obv,
                                                       const void* __restrict__ bo, size_t obo,
                                                       const void* __restrict__ ba, size_t oba,
                                                       bf16* __restrict__ valueo,
                                                       bf16* __restrict__ offo,
                                                       bf16* __restrict__ attno,
                                                       int M, const int* __restrict__ flag) {
    const int K = 256;
    int isf32 = *flag;
    __shared__ __align__(16) char smem[32768];
    bf16* As = (bf16*)smem;               // [2][128][32]
    bf16* Bs = (bf16*)smem + 8192;
    int tid = threadIdx.x;
    int lane = tid & 63, wave = tid >> 6;
    int wm = (wave & 1) << 6, wn = (wave >> 1) << 6;
    int bx, by;
    xcd_remap(bx, by);
    int bm = by * 128;
    int isV = (bx < 2);
    int bn = isV ? bx * 128 : (bx - 2) * 128;    // value: 0,128; q: 0,128,256
    const bf16* A = isV ? xb : qb;
    const bf16* Wt = isV ? Wvt : Wqt;
    int q = lane >> 4, l15 = lane & 15;

    v4f acc[4][4];
#pragma unroll
    for (int i = 0; i < 4; ++i)
#pragma unroll
        for (int j = 0; j < 4; ++j) acc[i][j] = (v4f){0.f, 0.f, 0.f, 0.f};

    int r0 = tid >> 2, r1 = r0 + 64;
    int oct = (tid & 3) * 8;
    int am0 = bm + r0; if (am0 >= M) am0 = M - 1;
    int am1 = bm + r1; if (am1 >= M) am1 = M - 1;
    const bf16* ag0 = A + (size_t)am0 * K + oct;
    const bf16* ag1 = A + (size_t)am1 * K + oct;
    const bf16* bg0 = Wt + (size_t)(bn + r0) * K + oct;
    const bf16* bg1 = Wt + (size_t)(bn + r1) * K + oct;
    bf16* lA0 = As + tid * 8;
    bf16* lA1 = As + (tid + 256) * 8;
    bf16* lA2 = As + 4096 + tid * 8;
    bf16* lA3 = As + 4096 + (tid + 256) * 8;
    bf16* lB0 = Bs + tid * 8;
    bf16* lB1 = Bs + (tid + 256) * 8;
    bf16* lB2 = Bs + 4096 + tid * 8;
    bf16* lB3 = Bs + 4096 + (tid + 256) * 8;

    for (int k0 = 0; k0 < K; k0 += 64) {
        GLDS16(ag0 + k0, lA0);
        GLDS16(ag1 + k0, lA1);
        GLDS16(ag0 + k0 + 32, lA2);
        GLDS16(ag1 + k0 + 32, lA3);
        GLDS16(bg0 + k0, lB0);
        GLDS16(bg1 + k0, lB1);
        GLDS16(bg0 + k0 + 32, lB2);
        GLDS16(bg1 + k0 + 32, lB3);
        __syncthreads();
#pragma unroll
        for (int h = 0; h < 2; ++h) {
            v8s a_frag[4], b_frag[4];
#pragma unroll
            for (int mi = 0; mi < 4; ++mi)
                a_frag[mi] = *(const v8s*)&As[h * 4096 + (wm + mi * 16 + l15) * 32 + q * 8];
#pragma unroll
            for (int ni = 0; ni < 4; ++ni)
                b_frag[ni] = *(const v8s*)&Bs[h * 4096 + (wn + ni * 16 + l15) * 32 + q * 8];
#pragma unroll
            for (int mi = 0; mi < 4; ++mi)
#pragma unroll
                for (int ni = 0; ni < 4; ++ni)
                    acc[mi][ni] = __builtin_amdgcn_mfma_f32_16x16x32_bf16(
                        a_frag[mi], b_frag[ni], acc[mi][ni], 0, 0, 0);
        }
        __syncthreads();
    }

    // block-uniform output routing + direct store
    bf16* outp; int outN, colbase; const void* bptr; size_t bofs;
    if (isV)             { outp = valueo; outN = 256; colbase = bn;       bptr = bv; bofs = obv; }
    else if (bn < 256)   { outp = offo;   outN = 256; colbase = bn;       bptr = bo; bofs = obo; }
    else                 { outp = attno;  outN = 128; colbase = bn - 256; bptr = ba; bofs = oba; }

    float bcol[4];
#pragma unroll
    for (int ni = 0; ni < 4; ++ni)
        bcol[ni] = ldin(bptr, bofs + colbase + wn + ni * 16 + l15, isf32);
#pragma unroll
    for (int mi = 0; mi < 4; ++mi) {
        int growb = bm + wm + mi * 16 + q * 4;
#pragma unroll
        for (int r = 0; r < 4; ++r) {
            int gm = growb + r;
            if (gm < M) {
                bf16* rowp = outp + (size_t)gm * outN + colbase + wn + l15;
#pragma unroll
                for (int ni = 0; ni < 4; ++ni)
                    rowp[ni * 16] = f2b(acc[mi][ni][r] + bcol[ni]);
            }
        }
    }
}

// ---------------- MFMA GEMM 64x64, BK=64 (8 blocks/CU capacity; for K=256 GEMMs: Wo) ----------------
__global__ void __launch_bounds__(256) mfma_gemm64(const bf16* __restrict__ A,
                                                   const bf16* __restrict__ Wt,
                                                   const void* __restrict__ bias, size_t boff,
                                                   bf16* __restrict__ C,
                                                   int M, int N, int K, int relu,
                                                   const int* __restrict__ flag) {
    int isf32 = *flag;
    __shared__ __align__(16) char smem[16384];   // As+Bs (16384) / Cs (9216) overlay
    bf16* As = (bf16*)smem;               // [2][64][32]
    bf16* Bs = (bf16*)smem + 4096;        // [2][64][32]
    bf16* Cs = (bf16*)smem;               // 64 x 72 (16B-aligned rows)
    int tid = threadIdx.x;
    int lane = tid & 63, wave = tid >> 6;
    int wm = (wave & 1) * 32, wn = (wave >> 1) * 32;
    int bx, by;
    xcd_remap(bx, by);
    int bm = by * 64, bn = bx * 64;
    int q = lane >> 4, l15 = lane & 15;

    v4f acc[2][2];
#pragma unroll
    for (int i = 0; i < 2; ++i)
#pragma unroll
        for (int j = 0; j < 2; ++j) acc[i][j] = (v4f){0.f, 0.f, 0.f, 0.f};

    int srow = tid >> 2;
    int oct = (tid & 3) * 8;
    int am = bm + srow; if (am >= M) am = M - 1;
    const bf16* arow = A + (size_t)am * K + oct;
    const bf16* brow = Wt + (size_t)(bn + srow) * K + oct;
    bf16* lA0 = As + tid * 8;
    bf16* lA1 = As + 2048 + tid * 8;
    bf16* lB0 = Bs + tid * 8;
    bf16* lB1 = Bs + 2048 + tid * 8;

    for (int k0 = 0; k0 < K; k0 += 64) {
        GLDS16(arow + k0, lA0);
        GLDS16(arow + k0 + 32, lA1);
        GLDS16(brow + k0, lB0);
        GLDS16(brow + k0 + 32, lB1);
        __syncthreads();
#pragma unroll
        for (int h = 0; h < 2; ++h) {
            v8s a_frag[2], b_frag[2];
#pragma unroll
            for (int mi = 0; mi < 2; ++mi)
                a_frag[mi] = *(const v8s*)&As[h * 2048 + (wm + mi * 16 + l15) * 32 + q * 8];
#pragma unroll
            for (int ni = 0; ni < 2; ++ni)
                b_frag[ni] = *(const v8s*)&Bs[h * 2048 + (wn + ni * 16 + l15) * 32 + q * 8];
#pragma unroll
            for (int mi = 0; mi < 2; ++mi)
#pragma unroll
                for (int ni = 0; ni < 2; ++ni)
                    acc[mi][ni] = __builtin_amdgcn_mfma_f32_16x16x32_bf16(
                        a_frag[mi], b_frag[ni], acc[mi][ni], 0, 0, 0);
        }
        __syncthreads();
    }

#pragma unroll
    for (int ni = 0; ni < 2; ++ni) {
        int cn = wn + ni * 16 + l15;
        float bv = ldin(bias, boff + bn + cn, isf32);
#pragma unroll
        for (int mi = 0; mi < 2; ++mi) {
#pragma unroll
            for (int r = 0; r < 4; ++r) {
                float v = acc[mi][ni][r] + bv;
                if (relu) v = fmaxf(v, 0.f);
                Cs[(wm + mi * 16 + q * 4 + r) * 72 + cn] = f2b(v);
            }
        }
    }
    __syncthreads();
    {
        int row = tid >> 2, seg = tid & 3;
        int gm = bm + row;
        if (gm < M) {
            const bf16* srcp = Cs + row * 72 + seg * 16;
            bf16* dstp = C + (size_t)gm * N + bn + seg * 16;
            *(uint4*)(dstp) = *(const uint4*)(srcp);
            *(uint4*)(dstp + 8) = *(const uint4*)(srcp + 8);
        }
    }
}

// ---------------- MFMA GEMM 64x64, BK=128 (for FFN2: K=2048, grid 3.7/CU < 5-block cap) ----------------
__global__ void __launch_bounds__(256) mfma_gemm64k(const bf16* __restrict__ A,
                                                    const bf16* __restrict__ Wt,
                                                    const void* __restrict__ bias, size_t boff,
                                                    bf16* __restrict__ C,
                                                    int M, int N, int K, int relu,
                                                    const int* __restrict__ flag) {
    int isf32 = *flag;
    __shared__ __align__(16) char smem[32768];   // As [4][64][32] + Bs [4][64][32]; Cs overlay
    bf16* As = (bf16*)smem;
    bf16* Bs = (bf16*)smem + 8192;
    bf16* Cs = (bf16*)smem;               // 64 x 72
    int tid = threadIdx.x;
    int lane = tid & 63, wave = tid >> 6;
    int wm = (wave & 1) * 32, wn = (wave >> 1) * 32;
    int bx, by;
    xcd_remap(bx, by);
    int bm = by * 64, bn = bx * 64;
    int q = lane >> 4, l15 = lane & 15;

    v4f acc[2][2];
#pragma unroll
    for (int i = 0; i < 2; ++i)
#pragma unroll
        for (int j = 0; j < 2; ++j) acc[i][j] = (v4f){0.f, 0.f, 0.f, 0.f};

    int srow = tid >> 2;
    int oct = (tid & 3) * 8;
    int am = bm + srow; if (am >= M) am = M - 1;
    const bf16* arow = A + (size_t)am * K + oct;
    const bf16* brow = Wt + (size_t)(bn + srow) * K + oct;

    for (int k0 = 0; k0 < K; k0 += 128) {
#pragma unroll
        for (int h = 0; h < 4; ++h) {
            GLDS16(arow + k0 + h * 32, As + h * 2048 + tid * 8);
            GLDS16(brow + k0 + h * 32, Bs + h * 2048 + tid * 8);
        }
        __syncthreads();
#pragma unroll
        for (int h = 0; h < 4; ++h) {
            v8s a_frag[2], b_frag[2];
#pragma unroll
            for (int mi = 0; mi < 2; ++mi)
                a_frag[mi] = *(const v8s*)&As[h * 2048 + (wm + mi * 16 + l15) * 32 + q * 8];
#pragma unroll
            for (int ni = 0; ni < 2; ++ni)
                b_frag[ni] = *(const v8s*)&Bs[h * 2048 + (wn + ni * 16 + l15) * 32 + q * 8];
#pragma unroll
            for (int mi = 0; mi < 2; ++mi)
#pragma unroll
                for (int ni = 0; ni < 2; ++ni)
                    acc[mi][ni] = __builtin_amdgcn_mfma_f32_16x16x32_bf16(
                        a_frag[mi], b_frag[ni], acc[mi][ni], 0, 0, 0);
        }
        __syncthreads();
    }

#pragma unroll
    for (int ni = 0; ni < 2; ++ni) {
        int cn = wn + ni * 16 + l15;
        float bv = ldin(bias, boff + bn + cn, isf32);
#pragma unroll
        for (int mi = 0; mi < 2; ++mi) {
#pragma unroll
            for (int r = 0; r < 4; ++r) {
                float v = acc[mi][ni][r] + bv;
                if (relu) v = fmaxf(v, 0.f);
                Cs[(wm + mi * 16 + q * 4 + r) * 72 + cn] = f2b(v);
            }
        }
    }
    __syncthreads();
    {
        int row = tid >> 2, seg = tid & 3;
        int gm = bm + row;
        if (gm < M) {
            const bf16* srcp = Cs + row * 72 + seg * 16;
            bf16* dstp = C + (size_t)gm * N + bn + seg * 16;
            *(uint4*)(dstp) = *(const uint4*)(srcp);
            *(uint4*)(dstp + 8) = *(const uint4*)(srcp + 8);
        }
    }
}

// ---------------- fallback VALU GEMM ----------------
template<typename TA, int ADDPOS, int RELU>
__global__ void __launch_bounds__(256) gemm_bias(const TA* __restrict__ A,
                                                 const bf16* __restrict__ Apos,
                                                 const void* __restrict__ W, size_t woff,
                                                 const void* __restrict__ bias, size_t boff,
                                                 bf16* __restrict__ C,
                                                 int M, int N, int K,
                                                 const int* __restrict__ flag) {
    int isf32 = *flag;
    __shared__ float As[16][65];
    __shared__ float Bs[16][65];
    int tid = threadIdx.x;
    int tx = tid & 15;
    int ty = tid >> 4;
    int bm = blockIdx.y * 64;
    int bn = blockIdx.x * 64;
    float acc[4][4] = {};
    for (int k0 = 0; k0 < K; k0 += 16) {
#pragma unroll
        for (int e = 0; e < 4; ++e) {
            int idx = tid + e * 256;
            int mm = idx >> 4;
            int kk = idx & 15;
            int gm = bm + mm;
            float av = 0.f;
            if (gm < M) {
                size_t ai = (size_t)gm * K + k0 + kk;
                if (sizeof(TA) == 4) av = ((const float*)A)[ai];
                else                 av = b2f(((const bf16*)A)[ai]);
                if (ADDPOS) av += b2f(Apos[ai]);
            }
            As[kk][mm] = av;
        }
#pragma unroll
        for (int e = 0; e < 4; ++e) {
            int idx = tid + e * 256;
            int kk = idx >> 6;
            int nn = idx & 63;
            int gn = bn + nn;
            Bs[kk][nn] = (gn < N) ? ldin(W, woff + (size_t)(k0 + kk) * N + gn, isf32) : 0.f;
        }
        __syncthreads();
#pragma unroll
        for (int kk = 0; kk < 16; ++kk) {
            float a[4], b[4];
#pragma unroll
            for (int i = 0; i < 4; ++i) a[i] = As[kk][ty + 16 * i];
#pragma unroll
            for (int j = 0; j < 4; ++j) b[j] = Bs[kk][tx + 16 * j];
#pragma unroll
            for (int i = 0; i < 4; ++i)
#pragma unroll
                for (int j = 0; j < 4; ++j) acc[i][j] += a[i] * b[j];
        }
        __syncthreads();
    }
#pragma unroll
    for (int i = 0; i < 4; ++i) {
        int gm = bm + ty + 16 * i;
        if (gm >= M) continue;
#pragma unroll
        for (int j = 0; j < 4; ++j) {
            int gn = bn + tx + 16 * j;
            if (gn >= N) continue;
            float v = acc[i][j] + ldin(bias, boff + gn, isf32);
            if (RELU) v = fmaxf(v, 0.f);
            C[(size_t)gm * N + gn] = f2b(v);
        }
    }
}

// ---------------- MS-deform sampling: 4 rows/block, 16B gathers + pair reduce ----------------
__global__ void __launch_bounds__(256) msdeform_sample4(const bf16* __restrict__ value,
                                                        const bf16* __restrict__ off,
                                                        const bf16* __restrict__ logits,
                                                        const float* __restrict__ refpts,
                                                        bf16* __restrict__ out) {
    __shared__ float sAttn[4 * 128];
    __shared__ int2 sIW[4 * 520];
    const int LH[4] = {76, 38, 19, 1};
    const int LW[4] = {76, 38, 19, 20};
    const int LS[4] = {0, 5776, 7220, 7581};
    int tid = threadIdx.x;
    int m0 = blockIdx.x * 4;

    for (int i = tid; i < 4 * 128; i += 256) {
        int r = i >> 7, li = i & 127;
        int m = m0 + r;
        int mc = (m < BM) ? m : BM - 1;
        sAttn[i] = b2f(logits[(size_t)mc * 128 + li]);
    }
    __syncthreads();
    {
        // 32 groups (4 rows x 8 heads) x 16 logits; 8 threads/group, 2 elems/thread.
        int g = tid >> 3, j = tid & 7;
        float* gp = sAttn + g * 16;
        float e0 = gp[j * 2], e1 = gp[j * 2 + 1];
        float mx = fmaxf(e0, e1);
#pragma unroll
        for (int o = 1; o < 8; o <<= 1) mx = fmaxf(mx, __shfl_xor(mx, o));
        e0 = __expf(e0 - mx);
        e1 = __expf(e1 - mx);
        float sm = e0 + e1;
#pragma unroll
        for (int o = 1; o < 8; o <<= 1) sm += __shfl_xor(sm, o);
        float inv = 1.f / sm;
        gp[j * 2] = e0 * inv;
        gp[j * 2 + 1] = e1 * inv;
    }
    __syncthreads();
    for (int i = tid; i < 4 * 128; i += 256) {
        int r = i >> 7, oi = i & 127;
        int m = m0 + r;
        int mc = (m < BM) ? m : BM - 1;
        int b = mc / S_TOT;
        int s = mc - b * S_TOT;
        int h = oi >> 4;
        int l = (oi >> 2) & 3;
        int H = LH[l], W = LW[l], st = LS[l];
        float fW = (float)W, fH = (float)H;
        float refx = refpts[s * 2 + 0];
        float refy = refpts[s * 2 + 1];
        ushort2 ov = *(const ushort2*)(off + (size_t)mc * 256 + oi * 2);
        float a = sAttn[r * 128 + oi];
        float xpix = (refx + b2f(ov.x) / fW) * fW - 0.5f;
        float ypix = (refy + b2f(ov.y) / fH) * fH - 0.5f;
        float x0f = floorf(xpix), y0f = floorf(ypix);
        int x0 = (int)x0f, y0 = (int)y0f;
        float wx1 = xpix - x0f, wy1 = ypix - y0f;
        float wx0 = 1.f - wx1, wy0 = 1.f - wy1;
        int vb = b * (S_TOT * 256) + h * 32;
        int base = r * 520 + h * 65 + (oi & 15) * 4;
#pragma unroll
        for (int c = 0; c < 4; ++c) {
            int cx = c & 1, cy = c >> 1;
            int xi = x0 + cx, yi = y0 + cy;
            float w = (cx ? wx1 : wx0) * (cy ? wy1 : wy0) * a;
            bool valid = (xi >= 0) && (xi <= W - 1) && (yi >= 0) && (yi <= H - 1);
            int xic = min(max(xi, 0), W - 1), yic = min(max(yi, 0), H - 1);
            int2 d;
            d.x = vb + (st + yic * W + xic) * 256;
            d.y = __float_as_int(valid ? w : 0.f);
            sIW[base + c] = d;
        }
    }
    __syncthreads();
    // gather: thread (r, h, chalf, d8grp): 8 channels x 32 corners (16B loads);
    // partner lanes (u ^ 4) hold the other 32 corners -> shfl_xor combine.
    int r = tid >> 6, u = tid & 63;
    int h = u >> 3, chalf = (u >> 2) & 1, d8 = (u & 3) * 8;
    int m = m0 + r;
    int cb = r * 520 + h * 65 + chalf * 32;
    float acc[8] = {0.f, 0.f, 0.f, 0.f, 0.f, 0.f, 0.f, 0.f};
#pragma unroll 8
    for (int c = 0; c < 32; ++c) {
        int2 p = sIW[cb + c];
        float w = __int_as_float(p.y);
        u16x8 v = *(const u16x8*)(value + p.x + d8);
#pragma unroll
        for (int k = 0; k < 8; ++k) acc[k] += w * b2f(v[k]);
    }
#pragma unroll
    for (int k = 0; k < 8; ++k) acc[k] += __shfl_xor(acc[k], 4);
    if (m < BM && chalf == 0) {
        u16x8 o;
#pragma unroll
        for (int k = 0; k < 8; ++k) o[k] = f2b(acc[k]);
        *(u16x8*)(out + (size_t)m * 256 + h * 32 + d8) = o;
    }
}

// ---------------- residual + LayerNorm: 4 rows/block; optional xb, qb, final-output ----------------
__global__ void __launch_bounds__(256) residual_ln4(float* __restrict__ x,
                                                    const bf16* __restrict__ y,
                                                    const void* __restrict__ g, size_t goff,
                                                    const void* __restrict__ beta, size_t boff,
                                                    const int* __restrict__ flag,
                                                    bf16* __restrict__ xb,
                                                    const bf16* __restrict__ pos,
                                                    bf16* __restrict__ qb,
                                                    void* __restrict__ fout) {
    int isf32 = *flag;
    int tid = threadIdx.x;
    int r = tid >> 6, lane = tid & 63;
    int m = blockIdx.x * 4 + r;
    if (m >= BM) return;
    size_t o = (size_t)m * 256 + lane * 4;
    float4 xv = *(const float4*)(x + o);
    ushort4 yv = *(const ushort4*)(y + o);
    float r0 = xv.x + b2f(yv.x), r1 = xv.y + b2f(yv.y);
    float r2 = xv.z + b2f(yv.z), r3 = xv.w + b2f(yv.w);
    float sum = r0 + r1 + r2 + r3;
#pragma unroll
    for (int ofs = 32; ofs > 0; ofs >>= 1) sum += __shfl_xor(sum, ofs);
    float mean = sum * (1.f / 256.f);
    float d0 = r0 - mean, d1 = r1 - mean, d2 = r2 - mean, d3 = r3 - mean;
    float vv = d0 * d0 + d1 * d1 + d2 * d2 + d3 * d3;
#pragma unroll
    for (int ofs = 32; ofs > 0; ofs >>= 1) vv += __shfl_xor(vv, ofs);
    float rstd = rsqrtf(vv * (1.f / 256.f) + 1e-5f);
    int c = lane * 4;
    float o0 = d0 * rstd * ldin(g, goff + c + 0, isf32) + ldin(beta, boff + c + 0, isf32);
    float o1 = d1 * rstd * ldin(g, goff + c + 1, isf32) + ldin(beta, boff + c + 1, isf32);
    float o2 = d2 * rstd * ldin(g, goff + c + 2, isf32) + ldin(beta, boff + c + 2, isf32);
    float o3 = d3 * rstd * ldin(g, goff + c + 3, isf32) + ldin(beta, boff + c + 3, isf32);
    if (fout) {
        if (isf32) {
            *(float4*)((float*)fout + o) = make_float4(o0, o1, o2, o3);
        } else {
            ushort4 fo;
            fo.x = f2b(o0); fo.y = f2b(o1); fo.z = f2b(o2); fo.w = f2b(o3);
            *(ushort4*)((bf16*)fout + o) = fo;
        }
        return;
    }
    *(float4*)(x + o) = make_float4(o0, o1, o2, o3);
    if (xb) {
        ushort4 xo;
        xo.x = f2b(o0); xo.y = f2b(o1); xo.z = f2b(o2); xo.w = f2b(o3);
        *(ushort4*)(xb + o) = xo;
    }
    if (qb) {
        ushort4 pv = *(const ushort4*)(pos + o);
        ushort4 qo;
        qo.x = f2b(o0 + b2f(pv.x));
        qo.y = f2b(o1 + b2f(pv.y));
        qo.z = f2b(o2 + b2f(pv.z));
        qo.w = f2b(o3 + b2f(pv.w));
        *(ushort4*)(qb + o) = qo;
    }
}

// ---------------- host ----------------
extern "C" void kernel_launch(void* const* d_in, const int* in_sizes, int n_in,
                              void* d_out, int out_size, void* d_ws, size_t ws_size,
                              hipStream_t stream) {
    (void)in_sizes; (void)n_in; (void)out_size;
    const size_t MS = (size_t)BM * DMODEL;   // 3,891,712

    char* base = (char*)d_ws;
    int* flag    = (int*)base;    base += 256;
    float* x     = (float*)base;  base += MS * 4;
    bf16* value  = (bf16*)base;   base += MS * 2;
    bf16* attnl  = (bf16*)base;   base += (size_t)BM * 128 * 2;
    bf16* pos    = (bf16*)base;   base += MS * 2;
    bf16* offms  = (bf16*)base;   base += MS * 2;   // off -> msout in place
    bf16* yb     = (bf16*)base;   base += MS * 2;   // also qb (dead before Wo writes)
    size_t base_used = (size_t)(base - (char*)d_ws);

    // transposed-weight element counts per layer
    const size_t SZ_WVT = 65536, SZ_WQT = 98304, SZ_WOT = 65536, SZ_W1T = 524288, SZ_W2T = 524288;
    const size_t WB1 = (SZ_WVT + SZ_WQT + SZ_WOT + SZ_W1T + SZ_W2T) * 2;   // bytes per layer

    bf16* xb = (bf16*)base;
    size_t needB  = base_used + MS * 2 + WB1 + (size_t)S_TOT * 8 + 1024;
    size_t needAH = ((base_used + MS * 2 + 6 * WB1 + (size_t)S_TOT * 8 + 1024 + 255) & ~(size_t)255)
                  + (size_t)BM * 2048 * 2;
    bool FAST = ws_size >= needB;
    bool W6   = ws_size >= needAH;      // 6-layer weights + full hidden
    int  nL   = W6 ? 6 : 1;

    bf16 *W1t = nullptr, *W2t = nullptr, *Wvt = nullptr, *Wqt = nullptr, *Wot = nullptr;
    float* ref;
    bf16* hiddenF = nullptr;
    bool FULLH = false;
    if (FAST) {
        char* p = (char*)xb + MS * 2;
        Wvt = (bf16*)p;  p += (size_t)nL * SZ_WVT * 2;
        Wqt = (bf16*)p;  p += (size_t)nL * SZ_WQT * 2;
        Wot = (bf16*)p;  p += (size_t)nL * SZ_WOT * 2;
        W1t = (bf16*)p;  p += (size_t)nL * SZ_W1T * 2;
        W2t = (bf16*)p;  p += (size_t)nL * SZ_W2T * 2;
        ref = (float*)p; p += (size_t)S_TOT * 2 * 4;
        size_t used = (size_t)(p - (char*)d_ws);
        used = (used + 255) & ~(size_t)255;
        if (ws_size >= used + (size_t)BM * 2048 * 2) {
            hiddenF = (bf16*)((char*)d_ws + used);
            FULLH = true;
        }
    } else {
        ref = (float*)base;
    }

    bf16* hidden = FULLH ? hiddenF : value;
    const int CH = FULLH ? BM : 2816;

    detect_dtype<<<1, 256, 0, stream>>>((const unsigned short*)d_in[0], flag);

    {
        int HW0 = 76 * 76, HW1 = 38 * 38, HW2 = 19 * 19;
        int n0 = BATCH * HW0 * 256, n1 = BATCH * HW1 * 256, n2 = BATCH * HW2 * 256;
        pack_level<<<(n0 + 255) / 256, 256, 0, stream>>>(d_in[0], d_in[1], d_in[8], 0, x, pos, HW0, 0, flag);
        pack_level<<<(n1 + 255) / 256, 256, 0, stream>>>(d_in[2], d_in[3], d_in[8], 1, x, pos, HW1, 5776, flag);
        pack_level<<<(n2 + 255) / 256, 256, 0, stream>>>(d_in[4], d_in[5], d_in[8], 2, x, pos, HW2, 7220, flag);
        int nt = BATCH * 20 * 256;
        pack_task<<<(nt + 255) / 256, 256, 0, stream>>>(d_in[6], d_in[7], x, pos, flag);
        make_ref<<<(S_TOT + 255) / 256, 256, 0, stream>>>(ref);
    }

    const int GM64 = (BM + 63) / 64;      // 238
    const int GM128 = (BM + 127) / 128;   // 119
    const int GR4 = (BM + 3) / 4;         // 3801
    const int n4 = (int)(MS / 4);

    if (FAST) {
        cvt_xq<<<(n4 + 255) / 256, 256, 0, stream>>>(x, pos, xb, yb, n4);   // xb + qb (layer 0)
        if (W6) {   // all 6 layers' weight transposes upfront, one launch
            transpose_all<<<dim3(1248, 6), 256, 0, stream>>>(d_in[13], d_in[9], d_in[11], d_in[15],
                                                             d_in[17], d_in[19],
                                                             Wvt, Wqt, Wot, W1t, W2t, -1, flag);
        }
    }

    for (int L = 0; L < 6; ++L) {
        size_t oW256 = (size_t)L * 256 * 256, ob256 = (size_t)L * 256;
        size_t oW128 = (size_t)L * 256 * 128, ob128 = (size_t)L * 128;
        size_t oW1   = (size_t)L * 256 * 2048, ob1  = (size_t)L * 2048;
        size_t oW2   = (size_t)L * 2048 * 256;
        bool last = (L == 5);

        if (FAST) {
            bf16* WvtL = Wvt + (W6 ? (size_t)L * SZ_WVT : 0);
            bf16* WqtL = Wqt + (W6 ? (size_t)L * SZ_WQT : 0);
            bf16* WotL = Wot + (W6 ? (size_t)L * SZ_WOT : 0);
            bf16* W1tL = W1t + (W6 ? (size_t)L * SZ_W1T : 0);
            bf16* W2tL = W2t + (W6 ? (size_t)L * SZ_W2T : 0);
            if (!W6) {
                transpose_all<<<dim3(1248, 1), 256, 0, stream>>>(d_in[13], d_in[9], d_in[11], d_in[15],
                                                                 d_in[17], d_in[19],
                                                                 Wvt, Wqt, Wot, W1t, W2t, L, flag);
            }
            bf16* qb = yb;
            mfma_gemm_vq128<<<dim3(5, GM128), 256, 0, stream>>>(xb, qb, WvtL, WqtL,
                                                                d_in[14], ob256, d_in[10], ob256,
                                                                d_in[12], ob128,
                                                                value, offms, attnl, BM, flag);

            msdeform_sample4<<<GR4, 256, 0, stream>>>(value, offms, attnl, ref, offms);

            mfma_gemm64<<<dim3(4, GM64), 256, 0, stream>>>(offms, WotL, d_in[16], ob256, yb, BM, 256, 256, 0, flag);
            residual_ln4<<<GR4, 256, 0, stream>>>(x, yb, d_in[21], ob256, d_in[22], ob256, flag, xb,
                                                  nullptr, nullptr, nullptr);

            for (int r0 = 0; r0 < BM; r0 += CH) {
                int mc = BM - r0 < CH ? BM - r0 : CH;
                int gmc128 = (mc + 127) / 128;
                int gmc64 = (mc + 63) / 64;
                mfma_gemm<<<dim3(16, gmc128), 256, 0, stream>>>(xb + (size_t)r0 * 256, W1tL, d_in[18], ob1,
                                                                hidden, mc, 2048, 256, 1, flag);
                mfma_gemm64k<<<dim3(4, gmc64), 256, 0, stream>>>(hidden, W2tL, d_in[20], ob256,
                                                                 yb + (size_t)r0 * 256, mc, 256, 2048, 0, flag);
            }
            residual_ln4<<<GR4, 256, 0, stream>>>(x, yb, d_in[23], ob256, d_in[24], ob256, flag,
                                                  last ? nullptr : xb,
                                                  last ? nullptr : pos,
                                                  last ? nullptr : yb,
                                                  last ? d_out : nullptr);
        } else {
            dim3 g256(4, GM64);
            dim3 g128(2, GM64);
            gemm_bias<float, 0, 0><<<g256, 256, 0, stream>>>(x, nullptr, d_in[13], oW256, d_in[14], ob256,
                                                             value, BM, 256, 256, flag);
            gemm_bias<float, 1, 0><<<g256, 256, 0, stream>>>(x, pos, d_in[9], oW256, d_in[10], ob256,
                                                             offms, BM, 256, 256, flag);
            gemm_bias<float, 1, 0><<<g128, 256, 0, stream>>>(x, pos, d_in[11], oW128, d_in[12], ob128,
                                                             attnl, BM, 128, 256, flag);
            msdeform_sample4<<<GR4, 256, 0, stream>>>(value, offms, attnl, ref, offms);
            gemm_bias<bf16, 0, 0><<<g256, 256, 0, stream>>>(offms, nullptr, d_in[15], oW256, d_in[16], ob256,
                                                            yb, BM, 256, 256, flag);
            residual_ln4<<<GR4, 256, 0, stream>>>(x, yb, d_in[21], ob256, d_in[22], ob256, flag,
                                                  nullptr, nullptr, nullptr, nullptr);
            for (int r0 = 0; r0 < BM; r0 += CH) {
                int mc = BM - r0 < CH ? BM - r0 : CH;
                dim3 gh(32, (mc + 63) / 64);
                dim3 go(4, (mc + 63) / 64);
                gemm_bias<float, 0, 1><<<gh, 256, 0, stream>>>(x + (size_t)r0 * 256, nullptr, d_in[17], oW1,
                                                               d_in[18], ob1, hidden, mc, 2048, 256, flag);
                gemm_bias<bf16, 0, 0><<<go, 256, 0, stream>>>(hidden, nullptr, d_in[19], oW2, d_in[20], ob256,
                                                              yb + (size_t)r0 * 256, mc, 256, 2048, flag);
            }
            residual_ln4<<<GR4, 256, 0, stream>>>(x, yb, d_in[23], ob256, d_in[24], ob256, flag,
                                                  nullptr, nullptr, nullptr,
                                                  last ? d_out : nullptr);
        }
    }
}

// Round 9
// 1074.887 us; speedup vs baseline: 1.1189x; 1.0207x over previous
//
#include <hip/hip_runtime.h>

#define S_TOT 7601
#define BATCH 2
#define BM (BATCH * S_TOT)   // 15202
#define DMODEL 256

typedef unsigned short bf16;
typedef __attribute__((ext_vector_type(8))) short v8s;
typedef __attribute__((ext_vector_type(4))) float v4f;
typedef __attribute__((ext_vector_type(8))) unsigned short u16x8;

__device__ __forceinline__ float b2f(bf16 u) {
    union { unsigned int i; float f; } v;
    v.i = ((unsigned int)u) << 16;
    return v.f;
}
__device__ __forceinline__ bf16 f2b(float f) {
    union { unsigned int i; float f; } v;
    v.f = f;
    unsigned int r = v.i + 0x7FFFu + ((v.i >> 16) & 1u);
    return (bf16)(r >> 16);
}
__device__ __forceinline__ float ldin(const void* p, size_t i, int isf32) {
    return isf32 ? ((const float*)p)[i] : b2f(((const bf16*)p)[i]);
}

// async global->LDS, 16B per lane. LDS dest must be linear: wave-uniform base + lane*16.
#define GLDS16(gp, lp)                                                          \
    __builtin_amdgcn_global_load_lds(                                           \
        (const __attribute__((address_space(1))) unsigned int*)(gp),            \
        (__attribute__((address_space(3))) unsigned int*)(lp), 16, 0, 0)

// bijective XCD-chunked block remap (m204): consecutive logical blocks land on one XCD.
__device__ __forceinline__ void xcd_remap(int& bx, int& by) {
    int gx = gridDim.x, gy = gridDim.y;
    int nwg = gx * gy;
    int lin = blockIdx.y * gx + blockIdx.x;
    int q = nwg >> 3, r = nwg & 7;
    int xcd = lin & 7, idx = lin >> 3;
    int lin2 = (xcd < r ? xcd * (q + 1) : r * (q + 1) + (xcd - r) * q) + idx;
    bx = lin2 % gx;
    by = lin2 / gx;
}

// ---------------- dtype probe ----------------
__global__ void detect_dtype(const unsigned short* __restrict__ src, int* __restrict__ flag) {
    __shared__ int cnt;
    if (threadIdx.x == 0) cnt = 0;
    __syncthreads();
    int local = 0;
    for (int i = threadIdx.x; i < 16384; i += 256) {
        unsigned int e = (src[i] >> 7) & 0xFFu;
        if (e >= 143u) local++;
    }
    atomicAdd(&cnt, local);
    __syncthreads();
    if (threadIdx.x == 0) *flag = (cnt > 200) ? 1 : 0;
}

// ---------------- pack: (B,C,HW) -> (B,HW,C) via 32x32 LDS tile transpose ----------------
// Round-8 PMC: old per-channel-lane mapping read at stride HW*4 -> 4x cross-XCD over-fetch
// (FETCH 92.7MB vs 23.6 ideal), 40.6us. Tile transpose reads coalesced along s, writes
// coalesced along c. grid: (ceil(HW/32)*8, B).
__global__ void __launch_bounds__(256) pack_level(const void* __restrict__ src,
                                                  const void* __restrict__ pin,
                                                  const void* __restrict__ lemb, int lrow,
                                                  float* __restrict__ x,
                                                  bf16* __restrict__ pout,
                                                  int HW, int start,
                                                  const int* __restrict__ flag) {
    int isf32 = *flag;
    int ts = blockIdx.x >> 3;          // s-tile index
    int tc = (blockIdx.x & 7) * 32;    // channel-tile base
    int b = blockIdx.y;
    int s0 = ts * 32;
    __shared__ float tls[32][33];
    __shared__ float tlp[32][33];
    int r = threadIdx.x >> 3;          // 0..31: channel row (load) / s row (store)
    int c4 = (threadIdx.x & 7) * 4;    // 0..28 step 4
    // load: channel = tc+r, s = s0+c4+i  (16B contiguous per thread along s)
    size_t gbase = ((size_t)b * 256 + tc + r) * HW;
#pragma unroll
    for (int i = 0; i < 4; ++i) {
        int s = s0 + c4 + i;
        float sv = 0.f, pv = 0.f;
        if (s < HW) {
            sv = ldin(src, gbase + s, isf32);
            pv = ldin(pin, gbase + s, isf32);
        }
        tls[r][c4 + i] = sv;
        tlp[r][c4 + i] = pv;
    }
    __syncthreads();
    // store: s = s0+r, channels tc+c4..tc+c4+3 (16B float4 x-write, 8B pos-write)
    int s = s0 + r;
    if (s < HW) {
        size_t o = ((size_t)b * S_TOT + start + s) * 256 + tc + c4;
        float4 xv;
        xv.x = tls[c4 + 0][r];
        xv.y = tls[c4 + 1][r];
        xv.z = tls[c4 + 2][r];
        xv.w = tls[c4 + 3][r];
        ushort4 po;
        po.x = f2b(tlp[c4 + 0][r] + ldin(lemb, (size_t)lrow * 256 + tc + c4 + 0, isf32));
        po.y = f2b(tlp[c4 + 1][r] + ldin(lemb, (size_t)lrow * 256 + tc + c4 + 1, isf32));
        po.z = f2b(tlp[c4 + 2][r] + ldin(lemb, (size_t)lrow * 256 + tc + c4 + 2, isf32));
        po.w = f2b(tlp[c4 + 3][r] + ldin(lemb, (size_t)lrow * 256 + tc + c4 + 3, isf32));
        *(float4*)(x + o) = xv;
        *(ushort4*)(pout + o) = po;
    }
}

__global__ void __launch_bounds__(256) pack_task(const void* __restrict__ te,
                                                 const void* __restrict__ tpe,
                                                 float* __restrict__ x,
                                                 bf16* __restrict__ pout,
                                                 const int* __restrict__ flag) {
    int isf32 = *flag;
    int i = blockIdx.x * 256 + threadIdx.x;
    int total = BATCH * 20 * 256;
    if (i >= total) return;
    int c = i & 255;
    int t = (i >> 8) % 20;
    int b = (i >> 8) / 20;
    size_t o = ((size_t)b * S_TOT + 7581 + t) * 256 + c;
    x[o] = ldin(te, ((size_t)b * 20 + t) * 256 + c, isf32);
    pout[o] = f2b(ldin(tpe, (size_t)t * 256 + c, isf32));
}

__global__ void __launch_bounds__(256) make_ref(float* __restrict__ ref) {
    int s = blockIdx.x * 256 + threadIdx.x;
    if (s >= S_TOT) return;
    int H, W, st;
    if (s < 5776)      { H = 76; W = 76; st = 0; }
    else if (s < 7220) { H = 38; W = 38; st = 5776; }
    else if (s < 7581) { H = 19; W = 19; st = 7220; }
    else               { H = 1;  W = 20; st = 7581; }
    int r = s - st;
    int i = r / W, j = r % W;
    ref[s * 2 + 0] = (j + 0.5f) / (float)W;
    ref[s * 2 + 1] = (i + 0.5f) / (float)H;
}

// ---------------- cvt: xb = bf16(x), qb = bf16(x + pos) — single pass over x ----------------
__global__ void __launch_bounds__(256) cvt_xq(const float* __restrict__ x,
                                              const bf16* __restrict__ pos,
                                              bf16* __restrict__ xb,
                                              bf16* __restrict__ qb, int n4) {
    int i = blockIdx.x * 256 + threadIdx.x;
    if (i >= n4) return;
    float4 xv = ((const float4*)x)[i];
    ushort4 pv = ((const ushort4*)pos)[i];
    ushort4 xo, qo;
    xo.x = f2b(xv.x); xo.y = f2b(xv.y); xo.z = f2b(xv.z); xo.w = f2b(xv.w);
    qo.x = f2b(xv.x + b2f(pv.x));
    qo.y = f2b(xv.y + b2f(pv.y));
    qo.z = f2b(xv.z + b2f(pv.z));
    qo.w = f2b(xv.w + b2f(pv.w));
    ((ushort4*)xb)[i] = xo;
    ((ushort4*)qb)[i] = qo;
}

// ---------------- all-weights transpose: 1248 tiles of 32x32 per layer ----------------
// L0 >= 0: single layer L0, dst at base. L0 < 0: layer = blockIdx.y, dst offset by stride.
// Woff -> Wqt rows 0..255, Wa -> Wqt rows 256..383 (fused q-GEMM weight).
__global__ void __launch_bounds__(256) transpose_all(const void* __restrict__ Wv,
                                                     const void* __restrict__ Woff,
                                                     const void* __restrict__ Wa,
                                                     const void* __restrict__ Wo,
                                                     const void* __restrict__ W1,
                                                     const void* __restrict__ W2,
                                                     bf16* __restrict__ Wvt,
                                                     bf16* __restrict__ Wqt,
                                                     bf16* __restrict__ Wot,
                                                     bf16* __restrict__ W1t,
                                                     bf16* __restrict__ W2t,
                                                     int L0, const int* __restrict__ flag) {
    int isf32 = *flag;
    int L = (L0 >= 0) ? L0 : (int)blockIdx.y;
    size_t dl = (L0 >= 0) ? 0 : (size_t)blockIdx.y;
    int t = blockIdx.x;
    const void* src; bf16* dst; int K, N; size_t woff; int rowoff = 0;
    if (t < 64)        { src = Wv;   dst = Wvt + dl * 65536;  K = 256;  N = 256;  woff = (size_t)L * 65536; }
    else if (t < 128)  { src = Woff; dst = Wqt + dl * 98304;  K = 256;  N = 256;  woff = (size_t)L * 65536;  t -= 64; }
    else if (t < 160)  { src = Wa;   dst = Wqt + dl * 98304;  K = 256;  N = 128;  woff = (size_t)L * 32768;  rowoff = 256; t -= 128; }
    else if (t < 224)  { src = Wo;   dst = Wot + dl * 65536;  K = 256;  N = 256;  woff = (size_t)L * 65536;  t -= 160; }
    else if (t < 736)  { src = W1;   dst = W1t + dl * 524288; K = 256;  N = 2048; woff = (size_t)L * 524288; t -= 224; }
    else               { src = W2;   dst = W2t + dl * 524288; K = 2048; N = 256;  woff = (size_t)L * 524288; t -= 736; }
    int ntx = N >> 5;
    int tk = (t / ntx) * 32;
    int tn = (t % ntx) * 32;
    __shared__ float tl[32][33];
    int r = threadIdx.x >> 3;
    int c4 = (threadIdx.x & 7) * 4;
#pragma unroll
    for (int i = 0; i < 4; ++i)
        tl[r][c4 + i] = ldin(src, woff + (size_t)(tk + r) * N + tn + c4 + i, isf32);
    __syncthreads();
#pragma unroll
    for (int i = 0; i < 4; ++i)
        dst[(size_t)(tn + r + rowoff) * K + tk + c4 + i] = f2b(tl[c4 + i][r]);
}

// ---------------- MFMA GEMM 128x128, BK=64, direct-store epilogue (proven r7) ----------------
__global__ void __launch_bounds__(256) mfma_gemm(const bf16* __restrict__ A,
                                                 const bf16* __restrict__ Wt,
                                                 const void* __restrict__ bias, size_t boff,
                                                 bf16* __restrict__ C,
                                                 int M, int N, int K, int relu,
                                                 const int* __restrict__ flag) {
    int isf32 = *flag;
    __shared__ __align__(16) char smem[32768];   // As+Bs only
    bf16* As = (bf16*)smem;               // [2][128][32]
    bf16* Bs = (bf16*)smem + 8192;        // [2][128][32]
    int tid = threadIdx.x;
    int lane = tid & 63, wave = tid >> 6;
    int wm = (wave & 1) << 6, wn = (wave >> 1) << 6;
    int bx, by;
    xcd_remap(bx, by);
    int bm = by * 128, bn = bx * 128;
    int q = lane >> 4, l15 = lane & 15;

    v4f acc[4][4];
#pragma unroll
    for (int i = 0; i < 4; ++i)
#pragma unroll
        for (int j = 0; j < 4; ++j) acc[i][j] = (v4f){0.f, 0.f, 0.f, 0.f};

    int r0 = tid >> 2, r1 = r0 + 64;
    int oct = (tid & 3) * 8;
    int am0 = bm + r0; if (am0 >= M) am0 = M - 1;
    int am1 = bm + r1; if (am1 >= M) am1 = M - 1;
    const bf16* ag0 = A + (size_t)am0 * K + oct;
    const bf16* ag1 = A + (size_t)am1 * K + oct;
    const bf16* bg0 = Wt + (size_t)(bn + r0) * K + oct;
    const bf16* bg1 = Wt + (size_t)(bn + r1) * K + oct;
    bf16* lA0 = As + tid * 8;
    bf16* lA1 = As + (tid + 256) * 8;
    bf16* lA2 = As + 4096 + tid * 8;
    bf16* lA3 = As + 4096 + (tid + 256) * 8;
    bf16* lB0 = Bs + tid * 8;
    bf16* lB1 = Bs + (tid + 256) * 8;
    bf16* lB2 = Bs + 4096 + tid * 8;
    bf16* lB3 = Bs + 4096 + (tid + 256) * 8;

    for (int k0 = 0; k0 < K; k0 += 64) {
        GLDS16(ag0 + k0, lA0);
        GLDS16(ag1 + k0, lA1);
        GLDS16(ag0 + k0 + 32, lA2);
        GLDS16(ag1 + k0 + 32, lA3);
        GLDS16(bg0 + k0, lB0);
        GLDS16(bg1 + k0, lB1);
        GLDS16(bg0 + k0 + 32, lB2);
        GLDS16(bg1 + k0 + 32, lB3);
        __syncthreads();
#pragma unroll
        for (int h = 0; h < 2; ++h) {
            v8s a_frag[4], b_frag[4];
#pragma unroll
            for (int mi = 0; mi < 4; ++mi)
                a_frag[mi] = *(const v8s*)&As[h * 4096 + (wm + mi * 16 + l15) * 32 + q * 8];
#pragma unroll
            for (int ni = 0; ni < 4; ++ni)
                b_frag[ni] = *(const v8s*)&Bs[h * 4096 + (wn + ni * 16 + l15) * 32 + q * 8];
#pragma unroll
            for (int mi = 0; mi < 4; ++mi)
#pragma unroll
                for (int ni = 0; ni < 4; ++ni)
                    acc[mi][ni] = __builtin_amdgcn_mfma_f32_16x16x32_bf16(
                        a_frag[mi], b_frag[ni], acc[mi][ni], 0, 0, 0);
        }
        __syncthreads();
    }

    float bcol[4];
#pragma unroll
    for (int ni = 0; ni < 4; ++ni)
        bcol[ni] = ldin(bias, boff + bn + wn + ni * 16 + l15, isf32);
#pragma unroll
    for (int mi = 0; mi < 4; ++mi) {
        int growb = bm + wm + mi * 16 + q * 4;
#pragma unroll
        for (int r = 0; r < 4; ++r) {
            int gm = growb + r;
            if (gm < M) {
                bf16* rowp = C + (size_t)gm * N + bn + wn + l15;
#pragma unroll
                for (int ni = 0; ni < 4; ++ni) {
                    float v = acc[mi][ni][r] + bcol[ni];
                    if (relu) v = fmaxf(v, 0.f);
                    rowp[ni * 16] = f2b(v);
                }
            }
        }
    }
}

// ---------------- fused value + q GEMM, 128x128 tiles, direct-store, K=256 ----------------
// grid (5, 119): bx 0,1 -> value = xb @ Wvt (cols bx*128); bx 2,3 -> off; bx 4 -> attn.
__global__ void __launch_bounds__(256) mfma_gemm_vq128(const bf16* __restrict__ xb,
                                                       const bf16* __restrict__ qb,
                                                       const bf16* __restrict__ Wvt,
                                                       const bf16* __restrict__ Wqt,
                                                       const void* __restrict__ bv, size_t obv,
                                                       const void* __restrict__ bo, size_t obo,
                                                       const void* __restrict__ ba, size_t oba,
                                                       bf16* __restrict__ valueo,
                                                       bf16* __restrict__ offo,
                                                       bf16* __restrict__ attno,
                                                       int M, const int* __restrict__ flag) {
    const int K = 256;
    int isf32 = *flag;
    __shared__ __align__(16) char smem[32768];
    bf16* As = (bf16*)smem;               // [2][128][32]
    bf16* Bs = (bf16*)smem + 8192;
    int tid = threadIdx.x;
    int lane = tid & 63, wave = tid >> 6;
    int wm = (wave & 1) << 6, wn = (wave >> 1) << 6;
    int bx, by;
    xcd_remap(bx, by);
    int bm = by * 128;
    int isV = (bx < 2);
    int bn = isV ? bx * 128 : (bx - 2) * 128;    // value: 0,128; q: 0,128,256
    const bf16* A = isV ? xb : qb;
    const bf16* Wt = isV ? Wvt : Wqt;
    int q = lane >> 4, l15 = lane & 15;

    v4f acc[4][4];
#pragma unroll
    for (int i = 0; i < 4; ++i)
#pragma unroll
        for (int j = 0; j < 4; ++j) acc[i][j] = (v4f){0.f, 0.f, 0.f, 0.f};

    int r0 = tid >> 2, r1 = r0 + 64;
    int oct = (tid & 3) * 8;
    int am0 = bm + r0; if (am0 >= M) am0 = M - 1;
    int am1 = bm + r1; if (am1 >= M) am1 = M - 1;
    const bf16* ag0 = A + (size_t)am0 * K + oct;
    const bf16* ag1 = A + (size_t)am1 * K + oct;
    const bf16* bg0 = Wt + (size_t)(bn + r0) * K + oct;
    const bf16* bg1 = Wt + (size_t)(bn + r1) * K + oct;
    bf16* lA0 = As + tid * 8;
    bf16* lA1 = As + (tid + 256) * 8;
    bf16* lA2 = As + 4096 + tid * 8;
    bf16* lA3 = As + 4096 + (tid + 256) * 8;
    bf16* lB0 = Bs + tid * 8;
    bf16* lB1 = Bs + (tid + 256) * 8;
    bf16* lB2 = Bs + 4096 + tid * 8;
    bf16* lB3 = Bs + 4096 + (tid + 256) * 8;

    for (int k0 = 0; k0 < K; k0 += 64) {
        GLDS16(ag0 + k0, lA0);
        GLDS16(ag1 + k0, lA1);
        GLDS16(ag0 + k0 + 32, lA2);
        GLDS16(ag1 + k0 + 32, lA3);
        GLDS16(bg0 + k0, lB0);
        GLDS16(bg1 + k0, lB1);
        GLDS16(bg0 + k0 + 32, lB2);
        GLDS16(bg1 + k0 + 32, lB3);
        __syncthreads();
#pragma unroll
        for (int h = 0; h < 2; ++h) {
            v8s a_frag[4], b_frag[4];
#pragma unroll
            for (int mi = 0; mi < 4; ++mi)
                a_frag[mi] = *(const v8s*)&As[h * 4096 + (wm + mi * 16 + l15) * 32 + q * 8];
#pragma unroll
            for (int ni = 0; ni < 4; ++ni)
                b_frag[ni] = *(const v8s*)&Bs[h * 4096 + (wn + ni * 16 + l15) * 32 + q * 8];
#pragma unroll
            for (int mi = 0; mi < 4; ++mi)
#pragma unroll
                for (int ni = 0; ni < 4; ++ni)
                    acc[mi][ni] = __builtin_amdgcn_mfma_f32_16x16x32_bf16(
                        a_frag[mi], b_frag[ni], acc[mi][ni], 0, 0, 0);
        }
        __syncthreads();
    }

    // block-uniform output routing + direct store
    bf16* outp; int outN, colbase; const void* bptr; size_t bofs;
    if (isV)             { outp = valueo; outN = 256; colbase = bn;       bptr = bv; bofs = obv; }
    else if (bn < 256)   { outp = offo;   outN = 256; colbase = bn;       bptr = bo; bofs = obo; }
    else                 { outp = attno;  outN = 128; colbase = bn - 256; bptr = ba; bofs = oba; }

    float bcol[4];
#pragma unroll
    for (int ni = 0; ni < 4; ++ni)
        bcol[ni] = ldin(bptr, bofs + colbase + wn + ni * 16 + l15, isf32);
#pragma unroll
    for (int mi = 0; mi < 4; ++mi) {
        int growb = bm + wm + mi * 16 + q * 4;
#pragma unroll
        for (int r = 0; r < 4; ++r) {
            int gm = growb + r;
            if (gm < M) {
                bf16* rowp = outp + (size_t)gm * outN + colbase + wn + l15;
#pragma unroll
                for (int ni = 0; ni < 4; ++ni)
                    rowp[ni * 16] = f2b(acc[mi][ni][r] + bcol[ni]);
            }
        }
    }
}

// ---------------- MFMA GEMM 64x64, BK=64 (8 blocks/CU capacity; for K=256 GEMMs: Wo) ----------------
__global__ void __launch_bounds__(256) mfma_gemm64(const bf16* __restrict__ A,
                                                   const bf16* __restrict__ Wt,
                                                   const void* __restrict__ bias, size_t boff,
                                                   bf16* __restrict__ C,
                                                   int M, int N, int K, int relu,
                                                   const int* __restrict__ flag) {
    int isf32 = *flag;
    __shared__ __align__(16) char smem[16384];   // As+Bs (16384) / Cs (9216) overlay
    bf16* As = (bf16*)smem;               // [2][64][32]
    bf16* Bs = (bf16*)smem + 4096;        // [2][64][32]
    bf16* Cs = (bf16*)smem;               // 64 x 72 (16B-aligned rows)
    int tid = threadIdx.x;
    int lane = tid & 63, wave = tid >> 6;
    int wm = (wave & 1) * 32, wn = (wave >> 1) * 32;
    int bx, by;
    xcd_remap(bx, by);
    int bm = by * 64, bn = bx * 64;
    int q = lane >> 4, l15 = lane & 15;

    v4f acc[2][2];
#pragma unroll
    for (int i = 0; i < 2; ++i)
#pragma unroll
        for (int j = 0; j < 2; ++j) acc[i][j] = (v4f){0.f, 0.f, 0.f, 0.f};

    int srow = tid >> 2;
    int oct = (tid & 3) * 8;
    int am = bm + srow; if (am >= M) am = M - 1;
    const bf16* arow = A + (size_t)am * K + oct;
    const bf16* brow = Wt + (size_t)(bn + srow) * K + oct;
    bf16* lA0 = As + tid * 8;
    bf16* lA1 = As + 2048 + tid * 8;
    bf16* lB0 = Bs + tid * 8;
    bf16* lB1 = Bs + 2048 + tid * 8;

    for (int k0 = 0; k0 < K; k0 += 64) {
        GLDS16(arow + k0, lA0);
        GLDS16(arow + k0 + 32, lA1);
        GLDS16(brow + k0, lB0);
        GLDS16(brow + k0 + 32, lB1);
        __syncthreads();
#pragma unroll
        for (int h = 0; h < 2; ++h) {
            v8s a_frag[2], b_frag[2];
#pragma unroll
            for (int mi = 0; mi < 2; ++mi)
                a_frag[mi] = *(const v8s*)&As[h * 2048 + (wm + mi * 16 + l15) * 32 + q * 8];
#pragma unroll
            for (int ni = 0; ni < 2; ++ni)
                b_frag[ni] = *(const v8s*)&Bs[h * 2048 + (wn + ni * 16 + l15) * 32 + q * 8];
#pragma unroll
            for (int mi = 0; mi < 2; ++mi)
#pragma unroll
                for (int ni = 0; ni < 2; ++ni)
                    acc[mi][ni] = __builtin_amdgcn_mfma_f32_16x16x32_bf16(
                        a_frag[mi], b_frag[ni], acc[mi][ni], 0, 0, 0);
        }
        __syncthreads();
    }

#pragma unroll
    for (int ni = 0; ni < 2; ++ni) {
        int cn = wn + ni * 16 + l15;
        float bv = ldin(bias, boff + bn + cn, isf32);
#pragma unroll
        for (int mi = 0; mi < 2; ++mi) {
#pragma unroll
            for (int r = 0; r < 4; ++r) {
                float v = acc[mi][ni][r] + bv;
                if (relu) v = fmaxf(v, 0.f);
                Cs[(wm + mi * 16 + q * 4 + r) * 72 + cn] = f2b(v);
            }
        }
    }
    __syncthreads();
    {
        int row = tid >> 2, seg = tid & 3;
        int gm = bm + row;
        if (gm < M) {
            const bf16* srcp = Cs + row * 72 + seg * 16;
            bf16* dstp = C + (size_t)gm * N + bn + seg * 16;
            *(uint4*)(dstp) = *(const uint4*)(srcp);
            *(uint4*)(dstp + 8) = *(const uint4*)(srcp + 8);
        }
    }
}

// ---------------- MFMA GEMM 64x64, BK=128 (for FFN2: K=2048, grid 3.7/CU < 5-block cap) ----------------
__global__ void __launch_bounds__(256) mfma_gemm64k(const bf16* __restrict__ A,
                                                    const bf16* __restrict__ Wt,
                                                    const void* __restrict__ bias, size_t boff,
                                                    bf16* __restrict__ C,
                                                    int M, int N, int K, int relu,
                                                    const int* __restrict__ flag) {
    int isf32 = *flag;
    __shared__ __align__(16) char smem[32768];   // As [4][64][32] + Bs [4][64][32]; Cs overlay
    bf16* As = (bf16*)smem;
    bf16* Bs = (bf16*)smem + 8192;
    bf16* Cs = (bf16*)smem;               // 64 x 72
    int tid = threadIdx.x;
    int lane = tid & 63, wave = tid >> 6;
    int wm = (wave & 1) * 32, wn = (wave >> 1) * 32;
    int bx, by;
    xcd_remap(bx, by);
    int bm = by * 64, bn = bx * 64;
    int q = lane >> 4, l15 = lane & 15;

    v4f acc[2][2];
#pragma unroll
    for (int i = 0; i < 2; ++i)
#pragma unroll
        for (int j = 0; j < 2; ++j) acc[i][j] = (v4f){0.f, 0.f, 0.f, 0.f};

    int srow = tid >> 2;
    int oct = (tid & 3) * 8;
    int am = bm + srow; if (am >= M) am = M - 1;
    const bf16* arow = A + (size_t)am * K + oct;
    const bf16* brow = Wt + (size_t)(bn + srow) * K + oct;

    for (int k0 = 0; k0 < K; k0 += 128) {
#pragma unroll
        for (int h = 0; h < 4; ++h) {
            GLDS16(arow + k0 + h * 32, As + h * 2048 + tid * 8);
            GLDS16(brow + k0 + h * 32, Bs + h * 2048 + tid * 8);
        }
        __syncthreads();
#pragma unroll
        for (int h = 0; h < 4; ++h) {
            v8s a_frag[2], b_frag[2];
#pragma unroll
            for (int mi = 0; mi < 2; ++mi)
                a_frag[mi] = *(const v8s*)&As[h * 2048 + (wm + mi * 16 + l15) * 32 + q * 8];
#pragma unroll
            for (int ni = 0; ni < 2; ++ni)
                b_frag[ni] = *(const v8s*)&Bs[h * 2048 + (wn + ni * 16 + l15) * 32 + q * 8];
#pragma unroll
            for (int mi = 0; mi < 2; ++mi)
#pragma unroll
                for (int ni = 0; ni < 2; ++ni)
                    acc[mi][ni] = __builtin_amdgcn_mfma_f32_16x16x32_bf16(
                        a_frag[mi], b_frag[ni], acc[mi][ni], 0, 0, 0);
        }
        __syncthreads();
    }

#pragma unroll
    for (int ni = 0; ni < 2; ++ni) {
        int cn = wn + ni * 16 + l15;
        float bv = ldin(bias, boff + bn + cn, isf32);
#pragma unroll
        for (int mi = 0; mi < 2; ++mi) {
#pragma unroll
            for (int r = 0; r < 4; ++r) {
                float v = acc[mi][ni][r] + bv;
                if (relu) v = fmaxf(v, 0.f);
                Cs[(wm + mi * 16 + q * 4 + r) * 72 + cn] = f2b(v);
            }
        }
    }
    __syncthreads();
    {
        int row = tid >> 2, seg = tid & 3;
        int gm = bm + row;
        if (gm < M) {
            const bf16* srcp = Cs + row * 72 + seg * 16;
            bf16* dstp = C + (size_t)gm * N + bn + seg * 16;
            *(uint4*)(dstp) = *(const uint4*)(srcp);
            *(uint4*)(dstp + 8) = *(const uint4*)(srcp + 8);
        }
    }
}

// ---------------- fallback VALU GEMM ----------------
template<typename TA, int ADDPOS, int RELU>
__global__ void __launch_bounds__(256) gemm_bias(const TA* __restrict__ A,
                                                 const bf16* __restrict__ Apos,
                                                 const void* __restrict__ W, size_t woff,
                                                 const void* __restrict__ bias, size_t boff,
                                                 bf16* __restrict__ C,
                                                 int M, int N, int K,
                                                 const int* __restrict__ flag) {
    int isf32 = *flag;
    __shared__ float As[16][65];
    __shared__ float Bs[16][65];
    int tid = threadIdx.x;
    int tx = tid & 15;
    int ty = tid >> 4;
    int bm = blockIdx.y * 64;
    int bn = blockIdx.x * 64;
    float acc[4][4] = {};
    for (int k0 = 0; k0 < K; k0 += 16) {
#pragma unroll
        for (int e = 0; e < 4; ++e) {
            int idx = tid + e * 256;
            int mm = idx >> 4;
            int kk = idx & 15;
            int gm = bm + mm;
            float av = 0.f;
            if (gm < M) {
                size_t ai = (size_t)gm * K + k0 + kk;
                if (sizeof(TA) == 4) av = ((const float*)A)[ai];
                else                 av = b2f(((const bf16*)A)[ai]);
                if (ADDPOS) av += b2f(Apos[ai]);
            }
            As[kk][mm] = av;
        }
#pragma unroll
        for (int e = 0; e < 4; ++e) {
            int idx = tid + e * 256;
            int kk = idx >> 6;
            int nn = idx & 63;
            int gn = bn + nn;
            Bs[kk][nn] = (gn < N) ? ldin(W, woff + (size_t)(k0 + kk) * N + gn, isf32) : 0.f;
        }
        __syncthreads();
#pragma unroll
        for (int kk = 0; kk < 16; ++kk) {
            float a[4], b[4];
#pragma unroll
            for (int i = 0; i < 4; ++i) a[i] = As[kk][ty + 16 * i];
#pragma unroll
            for (int j = 0; j < 4; ++j) b[j] = Bs[kk][tx + 16 * j];
#pragma unroll
            for (int i = 0; i < 4; ++i)
#pragma unroll
                for (int j = 0; j < 4; ++j) acc[i][j] += a[i] * b[j];
        }
        __syncthreads();
    }
#pragma unroll
    for (int i = 0; i < 4; ++i) {
        int gm = bm + ty + 16 * i;
        if (gm >= M) continue;
#pragma unroll
        for (int j = 0; j < 4; ++j) {
            int gn = bn + tx + 16 * j;
            if (gn >= N) continue;
            float v = acc[i][j] + ldin(bias, boff + gn, isf32);
            if (RELU) v = fmaxf(v, 0.f);
            C[(size_t)gm * N + gn] = f2b(v);
        }
    }
}

// ---------------- MS-deform sampling: 4 rows/block, 16B gathers + pair reduce ----------------
__global__ void __launch_bounds__(256) msdeform_sample4(const bf16* __restrict__ value,
                                                        const bf16* __restrict__ off,
                                                        const bf16* __restrict__ logits,
                                                        const float* __restrict__ refpts,
                                                        bf16* __restrict__ out) {
    __shared__ float sAttn[4 * 128];
    __shared__ int2 sIW[4 * 520];
    const int LH[4] = {76, 38, 19, 1};
    const int LW[4] = {76, 38, 19, 20};
    const int LS[4] = {0, 5776, 7220, 7581};
    int tid = threadIdx.x;
    int m0 = blockIdx.x * 4;

    for (int i = tid; i < 4 * 128; i += 256) {
        int r = i >> 7, li = i & 127;
        int m = m0 + r;
        int mc = (m < BM) ? m : BM - 1;
        sAttn[i] = b2f(logits[(size_t)mc * 128 + li]);
    }
    __syncthreads();
    {
        // 32 groups (4 rows x 8 heads) x 16 logits; 8 threads/group, 2 elems/thread.
        int g = tid >> 3, j = tid & 7;
        float* gp = sAttn + g * 16;
        float e0 = gp[j * 2], e1 = gp[j * 2 + 1];
        float mx = fmaxf(e0, e1);
#pragma unroll
        for (int o = 1; o < 8; o <<= 1) mx = fmaxf(mx, __shfl_xor(mx, o));
        e0 = __expf(e0 - mx);
        e1 = __expf(e1 - mx);
        float sm = e0 + e1;
#pragma unroll
        for (int o = 1; o < 8; o <<= 1) sm += __shfl_xor(sm, o);
        float inv = 1.f / sm;
        gp[j * 2] = e0 * inv;
        gp[j * 2 + 1] = e1 * inv;
    }
    __syncthreads();
    for (int i = tid; i < 4 * 128; i += 256) {
        int r = i >> 7, oi = i & 127;
        int m = m0 + r;
        int mc = (m < BM) ? m : BM - 1;
        int b = mc / S_TOT;
        int s = mc - b * S_TOT;
        int h = oi >> 4;
        int l = (oi >> 2) & 3;
        int H = LH[l], W = LW[l], st = LS[l];
        float fW = (float)W, fH = (float)H;
        float refx = refpts[s * 2 + 0];
        float refy = refpts[s * 2 + 1];
        ushort2 ov = *(const ushort2*)(off + (size_t)mc * 256 + oi * 2);
        float a = sAttn[r * 128 + oi];
        float xpix = (refx + b2f(ov.x) / fW) * fW - 0.5f;
        float ypix = (refy + b2f(ov.y) / fH) * fH - 0.5f;
        float x0f = floorf(xpix), y0f = floorf(ypix);
        int x0 = (int)x0f, y0 = (int)y0f;
        float wx1 = xpix - x0f, wy1 = ypix - y0f;
        float wx0 = 1.f - wx1, wy0 = 1.f - wy1;
        int vb = b * (S_TOT * 256) + h * 32;
        int base = r * 520 + h * 65 + (oi & 15) * 4;
#pragma unroll
        for (int c = 0; c < 4; ++c) {
            int cx = c & 1, cy = c >> 1;
            int xi = x0 + cx, yi = y0 + cy;
            float w = (cx ? wx1 : wx0) * (cy ? wy1 : wy0) * a;
            bool valid = (xi >= 0) && (xi <= W - 1) && (yi >= 0) && (yi <= H - 1);
            int xic = min(max(xi, 0), W - 1), yic = min(max(yi, 0), H - 1);
            int2 d;
            d.x = vb + (st + yic * W + xic) * 256;
            d.y = __float_as_int(valid ? w : 0.f);
            sIW[base + c] = d;
        }
    }
    __syncthreads();
    // gather: thread (r, h, chalf, d8grp): 8 channels x 32 corners (16B loads);
    // partner lanes (u ^ 4) hold the other 32 corners -> shfl_xor combine.
    int r = tid >> 6, u = tid & 63;
    int h = u >> 3, chalf = (u >> 2) & 1, d8 = (u & 3) * 8;
    int m = m0 + r;
    int cb = r * 520 + h * 65 + chalf * 32;
    float acc[8] = {0.f, 0.f, 0.f, 0.f, 0.f, 0.f, 0.f, 0.f};
#pragma unroll 8
    for (int c = 0; c < 32; ++c) {
        int2 p = sIW[cb + c];
        float w = __int_as_float(p.y);
        u16x8 v = *(const u16x8*)(value + p.x + d8);
#pragma unroll
        for (int k = 0; k < 8; ++k) acc[k] += w * b2f(v[k]);
    }
#pragma unroll
    for (int k = 0; k < 8; ++k) acc[k] += __shfl_xor(acc[k], 4);
    if (m < BM && chalf == 0) {
        u16x8 o;
#pragma unroll
        for (int k = 0; k < 8; ++k) o[k] = f2b(acc[k]);
        *(u16x8*)(out + (size_t)m * 256 + h * 32 + d8) = o;
    }
}

// ---------------- residual + LayerNorm: 4 rows/block; optional xb, qb, final-output ----------------
__global__ void __launch_bounds__(256) residual_ln4(float* __restrict__ x,
                                                    const bf16* __restrict__ y,
                                                    const void* __restrict__ g, size_t goff,
                                                    const void* __restrict__ beta, size_t boff,
                                                    const int* __restrict__ flag,
                                                    bf16* __restrict__ xb,
                                                    const bf16* __restrict__ pos,
                                                    bf16* __restrict__ qb,
                                                    void* __restrict__ fout) {
    int isf32 = *flag;
    int tid = threadIdx.x;
    int r = tid >> 6, lane = tid & 63;
    int m = blockIdx.x * 4 + r;
    if (m >= BM) return;
    size_t o = (size_t)m * 256 + lane * 4;
    float4 xv = *(const float4*)(x + o);
    ushort4 yv = *(const ushort4*)(y + o);
    float r0 = xv.x + b2f(yv.x), r1 = xv.y + b2f(yv.y);
    float r2 = xv.z + b2f(yv.z), r3 = xv.w + b2f(yv.w);
    float sum = r0 + r1 + r2 + r3;
#pragma unroll
    for (int ofs = 32; ofs > 0; ofs >>= 1) sum += __shfl_xor(sum, ofs);
    float mean = sum * (1.f / 256.f);
    float d0 = r0 - mean, d1 = r1 - mean, d2 = r2 - mean, d3 = r3 - mean;
    float vv = d0 * d0 + d1 * d1 + d2 * d2 + d3 * d3;
#pragma unroll
    for (int ofs = 32; ofs > 0; ofs >>= 1) vv += __shfl_xor(vv, ofs);
    float rstd = rsqrtf(vv * (1.f / 256.f) + 1e-5f);
    int c = lane * 4;
    float o0 = d0 * rstd * ldin(g, goff + c + 0, isf32) + ldin(beta, boff + c + 0, isf32);
    float o1 = d1 * rstd * ldin(g, goff + c + 1, isf32) + ldin(beta, boff + c + 1, isf32);
    float o2 = d2 * rstd * ldin(g, goff + c + 2, isf32) + ldin(beta, boff + c + 2, isf32);
    float o3 = d3 * rstd * ldin(g, goff + c + 3, isf32) + ldin(beta, boff + c + 3, isf32);
    if (fout) {
        if (isf32) {
            *(float4*)((float*)fout + o) = make_float4(o0, o1, o2, o3);
        } else {
            ushort4 fo;
            fo.x = f2b(o0); fo.y = f2b(o1); fo.z = f2b(o2); fo.w = f2b(o3);
            *(ushort4*)((bf16*)fout + o) = fo;
        }
        return;
    }
    *(float4*)(x + o) = make_float4(o0, o1, o2, o3);
    if (xb) {
        ushort4 xo;
        xo.x = f2b(o0); xo.y = f2b(o1); xo.z = f2b(o2); xo.w = f2b(o3);
        *(ushort4*)(xb + o) = xo;
    }
    if (qb) {
        ushort4 pv = *(const ushort4*)(pos + o);
        ushort4 qo;
        qo.x = f2b(o0 + b2f(pv.x));
        qo.y = f2b(o1 + b2f(pv.y));
        qo.z = f2b(o2 + b2f(pv.z));
        qo.w = f2b(o3 + b2f(pv.w));
        *(ushort4*)(qb + o) = qo;
    }
}

// ---------------- host ----------------
extern "C" void kernel_launch(void* const* d_in, const int* in_sizes, int n_in,
                              void* d_out, int out_size, void* d_ws, size_t ws_size,
                              hipStream_t stream) {
    (void)in_sizes; (void)n_in; (void)out_size;
    const size_t MS = (size_t)BM * DMODEL;   // 3,891,712

    char* base = (char*)d_ws;
    int* flag    = (int*)base;    base += 256;
    float* x     = (float*)base;  base += MS * 4;
    bf16* value  = (bf16*)base;   base += MS * 2;
    bf16* attnl  = (bf16*)base;   base += (size_t)BM * 128 * 2;
    bf16* pos    = (bf16*)base;   base += MS * 2;
    bf16* offms  = (bf16*)base;   base += MS * 2;   // off -> msout in place
    bf16* yb     = (bf16*)base;   base += MS * 2;   // also qb (dead before Wo writes)
    size_t base_used = (size_t)(base - (char*)d_ws);

    // transposed-weight element counts per layer
    const size_t SZ_WVT = 65536, SZ_WQT = 98304, SZ_WOT = 65536, SZ_W1T = 524288, SZ_W2T = 524288;
    const size_t WB1 = (SZ_WVT + SZ_WQT + SZ_WOT + SZ_W1T + SZ_W2T) * 2;   // bytes per layer

    bf16* xb = (bf16*)base;
    size_t needB  = base_used + MS * 2 + WB1 + (size_t)S_TOT * 8 + 1024;
    size_t needAH = ((base_used + MS * 2 + 6 * WB1 + (size_t)S_TOT * 8 + 1024 + 255) & ~(size_t)255)
                  + (size_t)BM * 2048 * 2;
    bool FAST = ws_size >= needB;
    bool W6   = ws_size >= needAH;      // 6-layer weights + full hidden
    int  nL   = W6 ? 6 : 1;

    bf16 *W1t = nullptr, *W2t = nullptr, *Wvt = nullptr, *Wqt = nullptr, *Wot = nullptr;
    float* ref;
    bf16* hiddenF = nullptr;
    bool FULLH = false;
    if (FAST) {
        char* p = (char*)xb + MS * 2;
        Wvt = (bf16*)p;  p += (size_t)nL * SZ_WVT * 2;
        Wqt = (bf16*)p;  p += (size_t)nL * SZ_WQT * 2;
        Wot = (bf16*)p;  p += (size_t)nL * SZ_WOT * 2;
        W1t = (bf16*)p;  p += (size_t)nL * SZ_W1T * 2;
        W2t = (bf16*)p;  p += (size_t)nL * SZ_W2T * 2;
        ref = (float*)p; p += (size_t)S_TOT * 2 * 4;
        size_t used = (size_t)(p - (char*)d_ws);
        used = (used + 255) & ~(size_t)255;
        if (ws_size >= used + (size_t)BM * 2048 * 2) {
            hiddenF = (bf16*)((char*)d_ws + used);
            FULLH = true;
        }
    } else {
        ref = (float*)base;
    }

    bf16* hidden = FULLH ? hiddenF : value;
    const int CH = FULLH ? BM : 2816;

    detect_dtype<<<1, 256, 0, stream>>>((const unsigned short*)d_in[0], flag);

    {
        int HW0 = 76 * 76, HW1 = 38 * 38, HW2 = 19 * 19;
        pack_level<<<dim3(((HW0 + 31) / 32) * 8, BATCH), 256, 0, stream>>>(d_in[0], d_in[1], d_in[8], 0, x, pos, HW0, 0, flag);
        pack_level<<<dim3(((HW1 + 31) / 32) * 8, BATCH), 256, 0, stream>>>(d_in[2], d_in[3], d_in[8], 1, x, pos, HW1, 5776, flag);
        pack_level<<<dim3(((HW2 + 31) / 32) * 8, BATCH), 256, 0, stream>>>(d_in[4], d_in[5], d_in[8], 2, x, pos, HW2, 7220, flag);
        int nt = BATCH * 20 * 256;
        pack_task<<<(nt + 255) / 256, 256, 0, stream>>>(d_in[6], d_in[7], x, pos, flag);
        make_ref<<<(S_TOT + 255) / 256, 256, 0, stream>>>(ref);
    }

    const int GM64 = (BM + 63) / 64;      // 238
    const int GM128 = (BM + 127) / 128;   // 119
    const int GR4 = (BM + 3) / 4;         // 3801
    const int n4 = (int)(MS / 4);

    if (FAST) {
        cvt_xq<<<(n4 + 255) / 256, 256, 0, stream>>>(x, pos, xb, yb, n4);   // xb + qb (layer 0)
        if (W6) {   // all 6 layers' weight transposes upfront, one launch
            transpose_all<<<dim3(1248, 6), 256, 0, stream>>>(d_in[13], d_in[9], d_in[11], d_in[15],
                                                             d_in[17], d_in[19],
                                                             Wvt, Wqt, Wot, W1t, W2t, -1, flag);
        }
    }

    for (int L = 0; L < 6; ++L) {
        size_t oW256 = (size_t)L * 256 * 256, ob256 = (size_t)L * 256;
        size_t oW128 = (size_t)L * 256 * 128, ob128 = (size_t)L * 128;
        size_t oW1   = (size_t)L * 256 * 2048, ob1  = (size_t)L * 2048;
        size_t oW2   = (size_t)L * 2048 * 256;
        bool last = (L == 5);

        if (FAST) {
            bf16* WvtL = Wvt + (W6 ? (size_t)L * SZ_WVT : 0);
            bf16* WqtL = Wqt + (W6 ? (size_t)L * SZ_WQT : 0);
            bf16* WotL = Wot + (W6 ? (size_t)L * SZ_WOT : 0);
            bf16* W1tL = W1t + (W6 ? (size_t)L * SZ_W1T : 0);
            bf16* W2tL = W2t + (W6 ? (size_t)L * SZ_W2T : 0);
            if (!W6) {
                transpose_all<<<dim3(1248, 1), 256, 0, stream>>>(d_in[13], d_in[9], d_in[11], d_in[15],
                                                                 d_in[17], d_in[19],
                                                                 Wvt, Wqt, Wot, W1t, W2t, L, flag);
            }
            bf16* qb = yb;
            mfma_gemm_vq128<<<dim3(5, GM128), 256, 0, stream>>>(xb, qb, WvtL, WqtL,
                                                                d_in[14], ob256, d_in[10], ob256,
                                                                d_in[12], ob128,
                                                                value, offms, attnl, BM, flag);

            msdeform_sample4<<<GR4, 256, 0, stream>>>(value, offms, attnl, ref, offms);

            mfma_gemm64<<<dim3(4, GM64), 256, 0, stream>>>(offms, WotL, d_in[16], ob256, yb, BM, 256, 256, 0, flag);
            residual_ln4<<<GR4, 256, 0, stream>>>(x, yb, d_in[21], ob256, d_in[22], ob256, flag, xb,
                                                  nullptr, nullptr, nullptr);

            for (int r0 = 0; r0 < BM; r0 += CH) {
                int mc = BM - r0 < CH ? BM - r0 : CH;
                int gmc128 = (mc + 127) / 128;
                int gmc64 = (mc + 63) / 64;
                mfma_gemm<<<dim3(16, gmc128), 256, 0, stream>>>(xb + (size_t)r0 * 256, W1tL, d_in[18], ob1,
                                                                hidden, mc, 2048, 256, 1, flag);
                mfma_gemm64k<<<dim3(4, gmc64), 256, 0, stream>>>(hidden, W2tL, d_in[20], ob256,
                                                                 yb + (size_t)r0 * 256, mc, 256, 2048, 0, flag);
            }
            residual_ln4<<<GR4, 256, 0, stream>>>(x, yb, d_in[23], ob256, d_in[24], ob256, flag,
                                                  last ? nullptr : xb,
                                                  last ? nullptr : pos,
                                                  last ? nullptr : yb,
                                                  last ? d_out : nullptr);
        } else {
            dim3 g256(4, GM64);
            dim3 g128(2, GM64);
            gemm_bias<float, 0, 0><<<g256, 256, 0, stream>>>(x, nullptr, d_in[13], oW256, d_in[14], ob256,
                                                             value, BM, 256, 256, flag);
            gemm_bias<float, 1, 0><<<g256, 256, 0, stream>>>(x, pos, d_in[9], oW256, d_in[10], ob256,
                                                             offms, BM, 256, 256, flag);
            gemm_bias<float, 1, 0><<<g128, 256, 0, stream>>>(x, pos, d_in[11], oW128, d_in[12], ob128,
                                                             attnl, BM, 128, 256, flag);
            msdeform_sample4<<<GR4, 256, 0, stream>>>(value, offms, attnl, ref, offms);
            gemm_bias<bf16, 0, 0><<<g256, 256, 0, stream>>>(offms, nullptr, d_in[15], oW256, d_in[16], ob256,
                                                            yb, BM, 256, 256, flag);
            residual_ln4<<<GR4, 256, 0, stream>>>(x, yb, d_in[21], ob256, d_in[22], ob256, flag,
                                                  nullptr, nullptr, nullptr, nullptr);
            for (int r0 = 0; r0 < BM; r0 += CH) {
                int mc = BM - r0 < CH ? BM - r0 : CH;
                dim3 gh(32, (mc + 63) / 64);
                dim3 go(4, (mc + 63) / 64);
                gemm_bias<float, 0, 1><<<gh, 256, 0, stream>>>(x + (size_t)r0 * 256, nullptr, d_in[17], oW1,
                                                               d_in[18], ob1, hidden, mc, 2048, 256, flag);
                gemm_bias<bf16, 0, 0><<<go, 256, 0, stream>>>(hidden, nullptr, d_in[19], oW2, d_in[20], ob256,
                                                              yb + (size_t)r0 * 256, mc, 256, 2048, flag);
            }
            residual_ln4<<<GR4, 256, 0, stream>>>(x, yb, d_in[23], ob256, d_in[24], ob256, flag,
                                                  nullptr, nullptr, nullptr,
                                                  last ? d_out : nullptr);
        }
    }
}